// Round 1
// 611.967 us; speedup vs baseline: 1.0277x; 1.0277x over previous
//
#include <hip/hip_runtime.h>
#include <hip/hip_bf16.h>
#include <cstddef>
#include <cfloat>

#define NW 80000
#define ND 16000
#define EWW 200000
#define EWD 200000

typedef short v8s __attribute__((ext_vector_type(8)));
typedef float v4f __attribute__((ext_vector_type(4)));

static __device__ __forceinline__ float blo(unsigned u) { return __uint_as_float(u << 16); }
static __device__ __forceinline__ float bhi(unsigned u) { return __uint_as_float(u & 0xffff0000u); }

// async global->LDS 16B copy: lane i of the wave writes lds_base + i*16
static __device__ __forceinline__ void gl2lds16(const void* g, void* l) {
    __builtin_amdgcn_global_load_lds((__attribute__((address_space(1))) void*)g,
                                     (__attribute__((address_space(3))) void*)l, 16, 0, 0);
}

// ---------- fp32 -> bf16 cast, x4 vectorized ----------
__global__ void cast_bf16_v4(const float4* __restrict__ x, uint2* __restrict__ xb, int n4) {
    int i = blockIdx.x * blockDim.x + threadIdx.x;
    if (i >= n4) return;
    float4 v = x[i];
    __hip_bfloat162 a, b;
    a.x = __float2bfloat16(v.x); a.y = __float2bfloat16(v.y);
    b.x = __float2bfloat16(v.z); b.y = __float2bfloat16(v.w);
    uint2 o;
    o.x = *(unsigned*)&a; o.y = *(unsigned*)&b;
    xb[i] = o;
}

// ---------- [Wa | Wb] ([K,512] each) -> Wt[1024,K] bf16 ----------
__global__ void transpose_w2(const float* __restrict__ Wa, const float* __restrict__ Wb,
                             __hip_bfloat16* __restrict__ Wt, int K) {
    int i = blockIdx.x * blockDim.x + threadIdx.x;
    if (i >= 1024 * K) return;
    int n = i / K, k = i - n * K;
    float v = (n < 512) ? Wa[k * 512 + n] : Wb[k * 512 + (n - 512)];
    Wt[i] = __float2bfloat16(v);
}

// ---------- Wr = per-head contraction of W with ar: [K,4] (dst side of wd) ----------
__global__ void make_wr(const float* __restrict__ W, const float* __restrict__ ar,
                        float* __restrict__ Wr, int K) {
    int i = blockIdx.x * blockDim.x + threadIdx.x;
    if (i >= K * 4) return;
    int k = i >> 2, h = i & 3;
    float sr = 0.f;
    const float* wr = W + (size_t)k * 512 + h * 128;
    const float* arr = ar + h * 128;
    for (int f = 0; f < 128; f++) sr += wr[f] * arr[f];
    Wr[k * 4 + h] = sr;
}

// ---------- er = x @ Wr ([N,4]); one wave per row; fp32 x ----------
__global__ __launch_bounds__(256) void attn_f32(const float* __restrict__ x,
                                                const float* __restrict__ Wv,
                                                float* __restrict__ out, int N, int K) {
    int wave = threadIdx.x >> 6, lane = threadIdx.x & 63;
    int row = blockIdx.x * 4 + wave;
    if (row >= N) return;
    const float* xr = x + (size_t)row * K;
    float a0 = 0.f, a1 = 0.f, a2 = 0.f, a3 = 0.f;
    for (int k = lane; k < K; k += 64) {
        float v = xr[k];
        const float* w = Wv + k * 4;
        a0 += v * w[0]; a1 += v * w[1]; a2 += v * w[2]; a3 += v * w[3];
    }
#pragma unroll
    for (int off = 32; off; off >>= 1) {
        a0 += __shfl_down(a0, off); a1 += __shfl_down(a1, off);
        a2 += __shfl_down(a2, off); a3 += __shfl_down(a3, off);
    }
    if (lane == 0) {
        out[row * 4 + 0] = a0; out[row * 4 + 1] = a1;
        out[row * 4 + 2] = a2; out[row * 4 + 3] = a3;
    }
}

// ---------- bf16-x variant ----------
__global__ __launch_bounds__(256) void attn_bf16(const __hip_bfloat16* __restrict__ x,
                                                 const float* __restrict__ Wv,
                                                 float* __restrict__ out, int N, int K) {
    int wave = threadIdx.x >> 6, lane = threadIdx.x & 63;
    int row = blockIdx.x * 4 + wave;
    if (row >= N) return;
    const __hip_bfloat16* xr = x + (size_t)row * K;
    float a0 = 0.f, a1 = 0.f, a2 = 0.f, a3 = 0.f;
    for (int k = lane; k < K; k += 64) {
        float v = __bfloat162float(xr[k]);
        const float* w = Wv + k * 4;
        a0 += v * w[0]; a1 += v * w[1]; a2 += v * w[2]; a3 += v * w[3];
    }
#pragma unroll
    for (int off = 32; off; off >>= 1) {
        a0 += __shfl_down(a0, off); a1 += __shfl_down(a1, off);
        a2 += __shfl_down(a2, off); a3 += __shfl_down(a3, off);
    }
    if (lane == 0) {
        out[row * 4 + 0] = a0; out[row * 4 + 1] = a1;
        out[row * 4 + 2] = a2; out[row * 4 + 3] = a3;
    }
}

// ---------- merged bf16 MFMA GEMM (both relations) + attention-logit epilogue ----------
// z[M,1024] = A[M,K] @ [W_ww | W_wd]  (Bt = concat^T [1024,K]).  BM=128, BK=64.
// Double-buffered LDS (T3-minimal 2-phase): per K-step, STAGE(next buf) is issued
// BEFORE the MFMAs on the current buf, so the global_load_lds queue drains during
// compute; a single __syncthreads per K-step (drains vmcnt + barriers) replaces
// the old stage->sync->compute->sync structure. Buffer index is a compile-time
// constant (explicit 2-sub-step loop) so alias analysis can't pessimize.
// 1-D grid, XCD-swizzled: super-tile of 64 blocks = 8 m-tiles x 8 heads laid out so
// the 8 head-blocks of one m-tile land on the same XCD -> A-tile hit in L2 7x.
__global__ __launch_bounds__(256) void gemm_epi(const __hip_bfloat16* __restrict__ A,
                                                const __hip_bfloat16* __restrict__ Bt,
                                                __hip_bfloat16* __restrict__ C,
                                                const float* __restrict__ al0,
                                                const float* __restrict__ ar0,
                                                const float* __restrict__ al1,
                                                float* __restrict__ el0,
                                                float* __restrict__ er0,
                                                float* __restrict__ el1,
                                                int M, int K) {
    const int N = 1024;
    __shared__ short AsF[2][128 * 64];   // 2 x 16 KB, row stride 64 shorts
    __shared__ short BsF[2][128 * 64];
    int tid = threadIdx.x;
    int wave = tid >> 6, lane = tid & 63;
    int l16 = lane & 15, quad = lane >> 4;

    // ---- XCD swizzle ----
    int MT = M >> 7;              // number of 128-row m-tiles
    int full = MT >> 3;           // full 8-m-tile super-groups
    int bid = blockIdx.x;
    int h, mt;
    if (bid < (full << 6)) {
        int s = bid >> 6, r = bid & 63;
        h = r >> 3;
        mt = (s << 3) | (r & 7);
    } else {
        int r2 = bid - (full << 6);
        int rem = MT - (full << 3);
        h = r2 / rem;
        mt = (full << 3) + (r2 - h * rem);
    }
    bool isww = h < 4;
    int hh = isww ? h : h - 4;
    int bm = mt * 128, bn = h * 128;
    v4f acc[2][8] = {};

    int laneR = lane >> 3;                 // 0..7
    int laneC = (lane & 7) ^ laneR;        // swizzled 16B-chunk index
    const __hip_bfloat16* ga = A  + (size_t)(bm + wave * 32 + laneR) * K + laneC * 8;
    const __hip_bfloat16* gb = Bt + (size_t)(bn + wave * 32 + laneR) * K + laneC * 8;
    int lofs = (wave * 32) * 64;           // short offset of this wave's 32-row slab

    auto STAGE = [&](int buf, int k0) {
#pragma unroll
        for (int j = 0; j < 4; j++) {
            gl2lds16(ga + (size_t)(j * 8) * K + k0, &AsF[buf][lofs + j * 512]);
            gl2lds16(gb + (size_t)(j * 8) * K + k0, &BsF[buf][lofs + j * 512]);
        }
    };
    auto COMPUTE = [&](int buf) {
#pragma unroll
        for (int kh = 0; kh < 2; kh++) {
            int s = (kh * 4 + quad) ^ (l16 & 7);
            v8s a[2], b[8];
#pragma unroll
            for (int rr = 0; rr < 2; rr++)
                a[rr] = *(const v8s*)&AsF[buf][(wave * 32 + rr * 16 + l16) * 64 + s * 8];
#pragma unroll
            for (int c = 0; c < 8; c++)
                b[c] = *(const v8s*)&BsF[buf][(c * 16 + l16) * 64 + s * 8];
#pragma unroll
            for (int rr = 0; rr < 2; rr++)
#pragma unroll
                for (int c = 0; c < 8; c++)
                    acc[rr][c] = __builtin_amdgcn_mfma_f32_16x16x32_bf16(a[rr], b[c], acc[rr][c], 0, 0, 0);
        }
    };

    // prologue: fill buf 0 with k=0
    STAGE(0, 0);
    __syncthreads();
    // main loop: 2 K-steps per iteration, compile-time buffer indices.
    // K is always a multiple of 128 here (256 or 128).
    for (int k0 = 0; k0 < K; k0 += 128) {
        if (k0 + 64 < K) STAGE(1, k0 + 64);
        COMPUTE(0);
        __syncthreads();
        if (k0 + 128 < K) STAGE(0, k0 + 128);
        COMPUTE(1);
        __syncthreads();
    }

    // store z (bf16)
#pragma unroll
    for (int rr = 0; rr < 2; rr++)
#pragma unroll
        for (int c = 0; c < 8; c++)
#pragma unroll
            for (int i = 0; i < 4; i++) {
                int row = bm + wave * 32 + rr * 16 + quad * 4 + i;
                int col = bn + c * 16 + l16;
                C[(size_t)row * N + col] = __float2bfloat16(acc[rr][c][i]);
            }
    // epilogue: el (and er for ww heads) via per-lane dot + 16-lane shuffle reduce
    const float* alp = isww ? al0 : al1;
    float* elp = isww ? el0 : el1;
    float* erp = isww ? er0 : nullptr;
    float alv[8], arv[8];
#pragma unroll
    for (int c = 0; c < 8; c++) {
        alv[c] = alp[hh * 128 + c * 16 + l16];
        arv[c] = isww ? ar0[hh * 128 + c * 16 + l16] : 0.f;
    }
#pragma unroll
    for (int rr = 0; rr < 2; rr++)
#pragma unroll
        for (int i = 0; i < 4; i++) {
            float pl = 0.f, pr = 0.f;
#pragma unroll
            for (int c = 0; c < 8; c++) {
                pl += acc[rr][c][i] * alv[c];
                pr += acc[rr][c][i] * arv[c];
            }
#pragma unroll
            for (int off = 1; off < 16; off <<= 1) {
                pl += __shfl_xor(pl, off);
                pr += __shfl_xor(pr, off);
            }
            if (l16 == 0) {
                int row = bm + wave * 32 + rr * 16 + quad * 4 + i;
                elp[(size_t)row * 4 + hh] = pl;
                if (erp) erp[(size_t)row * 4 + hh] = pr;
            }
        }
}

// ---------- CSR build ----------
__global__ void hist_k(const int* __restrict__ dst, int* __restrict__ deg, int E) {
    int t = blockIdx.x * blockDim.x + threadIdx.x;
    if (t < E) atomicAdd(&deg[dst[t]], 1);
}

// 3-phase exclusive scan: 1024 elems/block (256 thr x 4)
__global__ __launch_bounds__(256) void scan_block(const int* __restrict__ deg,
                                                  int* __restrict__ rp,
                                                  int* __restrict__ bsum, int N) {
    __shared__ int ts[256];
    int tid = threadIdx.x;
    int base = blockIdx.x * 1024 + tid * 4;
    int v0 = 0, v1 = 0, v2 = 0, v3 = 0;
    if (base + 3 < N) {
        int4 q = *(const int4*)(deg + base);
        v0 = q.x; v1 = q.y; v2 = q.z; v3 = q.w;
    } else {
        if (base + 0 < N) v0 = deg[base + 0];
        if (base + 1 < N) v1 = deg[base + 1];
        if (base + 2 < N) v2 = deg[base + 2];
        if (base + 3 < N) v3 = deg[base + 3];
    }
    int s = v0 + v1 + v2 + v3;
    ts[tid] = s;
    __syncthreads();
    for (int off = 1; off < 256; off <<= 1) {
        int t = (tid >= off) ? ts[tid - off] : 0;
        __syncthreads();
        ts[tid] += t;
        __syncthreads();
    }
    int excl = ts[tid] - s;
    if (tid == 255) bsum[blockIdx.x] = ts[255];
    if (base + 0 < N) rp[base + 0] = excl;
    if (base + 1 < N) rp[base + 1] = excl + v0;
    if (base + 2 < N) rp[base + 2] = excl + v0 + v1;
    if (base + 3 < N) rp[base + 3] = excl + v0 + v1 + v2;
}

__global__ __launch_bounds__(256) void scan_bsum(int* __restrict__ bsum, int nb) {
    __shared__ int ts[256];
    int tid = threadIdx.x;
    int v = (tid < nb) ? bsum[tid] : 0;
    ts[tid] = v;
    __syncthreads();
    for (int off = 1; off < 256; off <<= 1) {
        int t = (tid >= off) ? ts[tid - off] : 0;
        __syncthreads();
        ts[tid] += t;
        __syncthreads();
    }
    if (tid < nb) bsum[tid] = ts[tid] - v;
}

__global__ __launch_bounds__(256) void add_off(int* __restrict__ rp,
                                               const int* __restrict__ bsum,
                                               int N, int E) {
    int tid = threadIdx.x;
    int base = blockIdx.x * 1024 + tid * 4;
    int o = bsum[blockIdx.x];
    if (base + 3 < N) {
        int4 q = *(const int4*)(rp + base);
        q.x += o; q.y += o; q.z += o; q.w += o;
        *(int4*)(rp + base) = q;
    } else {
        if (base + 0 < N) rp[base + 0] += o;
        if (base + 1 < N) rp[base + 1] += o;
        if (base + 2 < N) rp[base + 2] += o;
        if (base + 3 < N) rp[base + 3] += o;
    }
    if (blockIdx.x == 0 && tid == 0) rp[N] = E;
}

__global__ void scatter_edges(const int* __restrict__ src, const int* __restrict__ dst,
                              const int* __restrict__ rp, int* __restrict__ cnt,
                              int* __restrict__ ss, int E) {
    int t = blockIdx.x * blockDim.x + threadIdx.x;
    if (t >= E) return;
    int d = dst[t];
    int pos = rp[d] + atomicAdd(&cnt[d], 1);
    ss[pos] = src[t];
}

// ---------- fused edge-softmax + aggregate: one wave per dst ----------
// Online softmax per (dst,head); depth-2 software pipeline: the src index is
// prefetched two edges ahead and the el / z-row loads for edge i+1 are ISSUED
// before edge i's accumulation, so each edge's load latency is hidden behind
// the previous edge's math + the load-queue slack.
__global__ __launch_bounds__(256) void softmax_agg(const int* __restrict__ rp,
                                                   const int* __restrict__ ss,
                                                   const float* __restrict__ el,
                                                   const float* __restrict__ er,
                                                   const __hip_bfloat16* __restrict__ z,
                                                   int zoff,
                                                   const float* __restrict__ b,
                                                   float* __restrict__ outf,
                                                   __hip_bfloat16* __restrict__ outb,
                                                   int Nd) {
    int wave = threadIdx.x >> 6, lane = threadIdx.x & 63;
    int d = blockIdx.x * 4 + wave;
    if (d >= Nd) return;
    int i0 = rp[d], i1 = rp[d + 1];
    float4 erd = *(const float4*)(er + (size_t)d * 4);
    float m[4], l[4], accx[4], accy[4];
#pragma unroll
    for (int h = 0; h < 4; h++) { m[h] = -FLT_MAX; l[h] = 0.f; accx[h] = 0.f; accy[h] = 0.f; }

    int sB = 0;
    float4 eA = make_float4(0.f, 0.f, 0.f, 0.f);
    unsigned uA0 = 0, uA1 = 0, uA2 = 0, uA3 = 0;
    if (i0 < i1) {
        int sA = ss[i0];
        sB = (i0 + 1 < i1) ? ss[i0 + 1] : sA;
        eA = *(const float4*)(el + (size_t)sA * 4);
        const unsigned* zr = (const unsigned*)(z + (size_t)sA * 1024 + zoff);
        uA0 = zr[lane]; uA1 = zr[64 + lane]; uA2 = zr[128 + lane]; uA3 = zr[192 + lane];
    }
    for (int i = i0; i < i1; i++) {
        int sC = (i + 2 < i1) ? ss[i + 2] : sB;          // prefetch src idx 2 ahead
        float4 eB = *(const float4*)(el + (size_t)sB * 4);  // issue next-edge loads now
        const unsigned* zrB = (const unsigned*)(z + (size_t)sB * 1024 + zoff);
        unsigned uB0 = zrB[lane], uB1 = zrB[64 + lane], uB2 = zrB[128 + lane], uB3 = zrB[192 + lane];

        unsigned u[4] = {uA0, uA1, uA2, uA3};
        float e[4] = {eA.x + erd.x, eA.y + erd.y, eA.z + erd.z, eA.w + erd.w};
#pragma unroll
        for (int h = 0; h < 4; h++) {
            float eh = e[h] > 0.f ? e[h] : 0.2f * e[h];   // leaky_relu(0.2)
            float nm = fmaxf(m[h], eh);
            float sc = __expf(m[h] - nm);
            float p  = __expf(eh - nm);
            m[h] = nm;
            l[h] = l[h] * sc + p;
            accx[h] = accx[h] * sc + p * blo(u[h]);
            accy[h] = accy[h] * sc + p * bhi(u[h]);
        }
        eA = eB; uA0 = uB0; uA1 = uB1; uA2 = uB2; uA3 = uB3;
        sB = sC;
    }
    int f = lane * 2;
    float ax = b[f] + b[128 + f] + b[256 + f] + b[384 + f];
    float ay = b[f + 1] + b[129 + f] + b[257 + f] + b[385 + f];
#pragma unroll
    for (int h = 0; h < 4; h++) {
        float inv = l[h] > 0.f ? 1.f / l[h] : 0.f;
        ax += accx[h] * inv;
        ay += accy[h] * inv;
    }
    ax = fmaxf(ax, 0.f);
    ay = fmaxf(ay, 0.f);
    if (outf) {
        *(float2*)(outf + (size_t)d * 128 + f) = make_float2(ax, ay);
    } else {
        __hip_bfloat162 p2;
        p2.x = __float2bfloat16(ax);
        p2.y = __float2bfloat16(ay);
        *(__hip_bfloat162*)(outb + (size_t)d * 128 + f) = p2;
    }
}

static inline char* aln(char*& p, size_t bytes) {
    char* r = p;
    p += (bytes + 255) & ~(size_t)255;
    return r;
}

static void build_csr(const int* src, const int* dst, int Nd, int E,
                      int* rp, int* deg, int* bsum, int* ss, hipStream_t stream) {
    hipMemsetAsync(deg, 0, (size_t)Nd * 2 * 4, stream);
    hist_k<<<(E + 255) / 256, 256, 0, stream>>>(dst, deg, E);
    int nb = (Nd + 1023) / 1024;
    scan_block<<<nb, 256, 0, stream>>>(deg, rp, bsum, Nd);
    scan_bsum<<<1, 256, 0, stream>>>(bsum, nb);
    add_off<<<nb, 256, 0, stream>>>(rp, bsum, Nd, E);
    scatter_edges<<<(E + 255) / 256, 256, 0, stream>>>(src, dst, rp, deg + Nd, ss, E);
}

extern "C" void kernel_launch(void* const* d_in, const int* in_sizes, int n_in,
                              void* d_out, int out_size, void* d_ws, size_t ws_size,
                              hipStream_t stream) {
    const float* xw     = (const float*)d_in[0];
    const float* xd     = (const float*)d_in[1];
    const float* W_ww0  = (const float*)d_in[2];
    const float* al_ww0 = (const float*)d_in[3];
    const float* ar_ww0 = (const float*)d_in[4];
    const float* b_ww0  = (const float*)d_in[5];
    const float* W_wd0  = (const float*)d_in[6];
    const float* al_wd0 = (const float*)d_in[7];
    const float* ar_wd0 = (const float*)d_in[8];
    const float* b_wd0  = (const float*)d_in[9];
    const float* W_ww1  = (const float*)d_in[10];
    const float* al_ww1 = (const float*)d_in[11];
    const float* ar_ww1 = (const float*)d_in[12];
    const float* b_ww1  = (const float*)d_in[13];
    const float* W_wd1  = (const float*)d_in[14];
    const float* al_wd1 = (const float*)d_in[15];
    const float* ar_wd1 = (const float*)d_in[16];
    const float* b_wd1  = (const float*)d_in[17];
    const int* ww_src   = (const int*)d_in[18];
    const int* ww_dst   = (const int*)d_in[19];
    const int* wd_src   = (const int*)d_in[20];
    const int* wd_dst   = (const int*)d_in[21];

    // ---- workspace carve ----
    char* p = (char*)d_ws;
    __hip_bfloat16* z    = (__hip_bfloat16*)aln(p, (size_t)NW * 1024 * 2);  // 164 MB
    __hip_bfloat16* xwb  = (__hip_bfloat16*)aln(p, (size_t)NW * 256 * 2);
    __hip_bfloat16* xw1b = (__hip_bfloat16*)aln(p, (size_t)NW * 128 * 2);
    __hip_bfloat16* xd1b = (__hip_bfloat16*)aln(p, (size_t)ND * 128 * 2);
    __hip_bfloat16* Wt   = (__hip_bfloat16*)aln(p, (size_t)1024 * 256 * 2);
    float* el0  = (float*)aln(p, (size_t)NW * 4 * 4);   // ww src logits
    float* er0  = (float*)aln(p, (size_t)NW * 4 * 4);   // ww dst logits
    float* el1  = (float*)aln(p, (size_t)NW * 4 * 4);   // wd src logits (word rows)
    float* er1  = (float*)aln(p, (size_t)ND * 4 * 4);   // wd dst logits (doc rows)
    float* Wr   = (float*)aln(p, 4096);
    // CSR ww
    int* rp_ww  = (int*)aln(p, (size_t)(NW + 1) * 4);
    int* deg_ww = (int*)aln(p, (size_t)NW * 2 * 4);   // deg + cnt, one memset
    int* ss_ww  = (int*)aln(p, (size_t)EWW * 4);
    // CSR wd
    int* rp_wd  = (int*)aln(p, (size_t)(ND + 1) * 4);
    int* deg_wd = (int*)aln(p, (size_t)ND * 2 * 4);
    int* ss_wd  = (int*)aln(p, (size_t)EWD * 4);
    int* bsum   = (int*)aln(p, 1024);

    float* out_xw = (float*)d_out;
    float* out_xd = out_xw + (size_t)NW * 128;

    // ---- cast input features ----
    cast_bf16_v4<<<(NW * 256 / 4 + 255) / 256, 256, 0, stream>>>(
        (const float4*)xw, (uint2*)xwb, NW * 256 / 4);

    // ---- CSR build (once per graph, reused by both layers) ----
    build_csr(ww_src, ww_dst, NW, EWW, rp_ww, deg_ww, bsum, ss_ww, stream);
    build_csr(wd_src, wd_dst, ND, EWD, rp_wd, deg_wd, bsum, ss_wd, stream);

    const int GEMM_BLOCKS = 8 * (NW / 128);   // 5000

    // ================= layer 0 (K=256) =================
    transpose_w2<<<(1024 * 256 + 255) / 256, 256, 0, stream>>>(W_ww0, W_wd0, Wt, 256);
    gemm_epi<<<GEMM_BLOCKS, 256, 0, stream>>>(xwb, Wt, z, al_ww0, ar_ww0, al_wd0,
                                              el0, er0, el1, NW, 256);
    make_wr<<<(256 * 4 + 255) / 256, 256, 0, stream>>>(W_wd0, ar_wd0, Wr, 256);
    attn_f32<<<(ND + 3) / 4, 256, 0, stream>>>(xd, Wr, er1, ND, 256);
    softmax_agg<<<(NW + 3) / 4, 256, 0, stream>>>(rp_ww, ss_ww, el0, er0, z, 0,
                                                  b_ww0, nullptr, xw1b, NW);
    softmax_agg<<<(ND + 3) / 4, 256, 0, stream>>>(rp_wd, ss_wd, el1, er1, z, 512,
                                                  b_wd0, nullptr, xd1b, ND);

    // ================= layer 1 (K=128) =================
    transpose_w2<<<(1024 * 128 + 255) / 256, 256, 0, stream>>>(W_ww1, W_wd1, Wt, 128);
    gemm_epi<<<GEMM_BLOCKS, 256, 0, stream>>>(xw1b, Wt, z, al_ww1, ar_ww1, al_wd1,
                                              el0, er0, el1, NW, 128);
    make_wr<<<(128 * 4 + 255) / 256, 256, 0, stream>>>(W_wd1, ar_wd1, Wr, 128);
    attn_bf16<<<(ND + 3) / 4, 256, 0, stream>>>(xd1b, Wr, er1, ND, 128);
    softmax_agg<<<(NW + 3) / 4, 256, 0, stream>>>(rp_ww, ss_ww, el0, er0, z, 0,
                                                  b_ww1, out_xw, nullptr, NW);
    softmax_agg<<<(ND + 3) / 4, 256, 0, stream>>>(rp_wd, ss_wd, el1, er1, z, 512,
                                                  b_wd1, out_xd, nullptr, ND);
}

// Round 2
// 611.966 us; speedup vs baseline: 1.0277x; 1.0000x over previous
//
#include <hip/hip_runtime.h>
#include <hip/hip_bf16.h>
#include <cstddef>
#include <cfloat>

#define NW 80000
#define ND 16000
#define EWW 200000
#define EWD 200000

typedef short v8s __attribute__((ext_vector_type(8)));
typedef float v4f __attribute__((ext_vector_type(4)));

static __device__ __forceinline__ float blo(unsigned u) { return __uint_as_float(u << 16); }
static __device__ __forceinline__ float bhi(unsigned u) { return __uint_as_float(u & 0xffff0000u); }

// async global->LDS 16B copy: lane i of the wave writes lds_base + i*16
static __device__ __forceinline__ void gl2lds16(const void* g, void* l) {
    __builtin_amdgcn_global_load_lds((__attribute__((address_space(1))) void*)g,
                                     (__attribute__((address_space(3))) void*)l, 16, 0, 0);
}

// ---------- fp32 -> bf16 cast, x4 vectorized ----------
__global__ void cast_bf16_v4(const float4* __restrict__ x, uint2* __restrict__ xb, int n4) {
    int i = blockIdx.x * blockDim.x + threadIdx.x;
    if (i >= n4) return;
    float4 v = x[i];
    __hip_bfloat162 a, b;
    a.x = __float2bfloat16(v.x); a.y = __float2bfloat16(v.y);
    b.x = __float2bfloat16(v.z); b.y = __float2bfloat16(v.w);
    uint2 o;
    o.x = *(unsigned*)&a; o.y = *(unsigned*)&b;
    xb[i] = o;
}

// ---------- [Wa | Wb] ([K,512] each) -> Wt[1024,K] bf16 ----------
__global__ void transpose_w2(const float* __restrict__ Wa, const float* __restrict__ Wb,
                             __hip_bfloat16* __restrict__ Wt, int K) {
    int i = blockIdx.x * blockDim.x + threadIdx.x;
    if (i >= 1024 * K) return;
    int n = i / K, k = i - n * K;
    float v = (n < 512) ? Wa[k * 512 + n] : Wb[k * 512 + (n - 512)];
    Wt[i] = __float2bfloat16(v);
}

// ---------- Wr = per-head contraction of W with ar: [K,4] (dst side of wd) ----------
__global__ void make_wr(const float* __restrict__ W, const float* __restrict__ ar,
                        float* __restrict__ Wr, int K) {
    int i = blockIdx.x * blockDim.x + threadIdx.x;
    if (i >= K * 4) return;
    int k = i >> 2, h = i & 3;
    float sr = 0.f;
    const float* wr = W + (size_t)k * 512 + h * 128;
    const float* arr = ar + h * 128;
    for (int f = 0; f < 128; f++) sr += wr[f] * arr[f];
    Wr[k * 4 + h] = sr;
}

// ---------- er = x @ Wr ([N,4]); one wave per row; fp32 x ----------
__global__ __launch_bounds__(256) void attn_f32(const float* __restrict__ x,
                                                const float* __restrict__ Wv,
                                                float* __restrict__ out, int N, int K) {
    int wave = threadIdx.x >> 6, lane = threadIdx.x & 63;
    int row = blockIdx.x * 4 + wave;
    if (row >= N) return;
    const float* xr = x + (size_t)row * K;
    float a0 = 0.f, a1 = 0.f, a2 = 0.f, a3 = 0.f;
    for (int k = lane; k < K; k += 64) {
        float v = xr[k];
        const float* w = Wv + k * 4;
        a0 += v * w[0]; a1 += v * w[1]; a2 += v * w[2]; a3 += v * w[3];
    }
#pragma unroll
    for (int off = 32; off; off >>= 1) {
        a0 += __shfl_down(a0, off); a1 += __shfl_down(a1, off);
        a2 += __shfl_down(a2, off); a3 += __shfl_down(a3, off);
    }
    if (lane == 0) {
        out[row * 4 + 0] = a0; out[row * 4 + 1] = a1;
        out[row * 4 + 2] = a2; out[row * 4 + 3] = a3;
    }
}

// ---------- bf16-x variant ----------
__global__ __launch_bounds__(256) void attn_bf16(const __hip_bfloat16* __restrict__ x,
                                                 const float* __restrict__ Wv,
                                                 float* __restrict__ out, int N, int K) {
    int wave = threadIdx.x >> 6, lane = threadIdx.x & 63;
    int row = blockIdx.x * 4 + wave;
    if (row >= N) return;
    const __hip_bfloat16* xr = x + (size_t)row * K;
    float a0 = 0.f, a1 = 0.f, a2 = 0.f, a3 = 0.f;
    for (int k = lane; k < K; k += 64) {
        float v = __bfloat162float(xr[k]);
        const float* w = Wv + k * 4;
        a0 += v * w[0]; a1 += v * w[1]; a2 += v * w[2]; a3 += v * w[3];
    }
#pragma unroll
    for (int off = 32; off; off >>= 1) {
        a0 += __shfl_down(a0, off); a1 += __shfl_down(a1, off);
        a2 += __shfl_down(a2, off); a3 += __shfl_down(a3, off);
    }
    if (lane == 0) {
        out[row * 4 + 0] = a0; out[row * 4 + 1] = a1;
        out[row * 4 + 2] = a2; out[row * 4 + 3] = a3;
    }
}

// ---------- merged bf16 MFMA GEMM (both relations) + attention-logit epilogue ----------
// z[M,1024] = A[M,K] @ [W_ww | W_wd]  (Bt = concat^T [1024,K]).  BM=128, BK=64.
// T3+T4 pipeline: double-buffered LDS with RAW s_barrier + counted s_waitcnt
// vmcnt(8) (never 0 in steady state) so the next tile's 8 global_load_lds stay
// in flight ACROSS the barrier — __syncthreads would drain vmcnt(0) and
// serialize stage/compute (measured: r1 neutral at 104us because of exactly that).
// Per tile: STAGE(next) -> vmcnt(8) [oldest 8 = current tile landed] -> barrier
// -> MFMA on current -> barrier [all waves done reading before restage].
// C writeback: accumulators re-staged through LDS (buffers are free after the
// K-loop) and written as 8 coalesced dwordx4 per thread instead of 64 scalar
// 2B stores (4x32B segments/wave-store -> 1KB contiguous/wave-store).
__global__ __launch_bounds__(256) void gemm_epi(const __hip_bfloat16* __restrict__ A,
                                                const __hip_bfloat16* __restrict__ Bt,
                                                __hip_bfloat16* __restrict__ C,
                                                const float* __restrict__ al0,
                                                const float* __restrict__ ar0,
                                                const float* __restrict__ al1,
                                                float* __restrict__ el0,
                                                float* __restrict__ er0,
                                                float* __restrict__ el1,
                                                int M, int K) {
    const int N = 1024;
    __shared__ short AsF[2][128 * 64];   // 2 x 16 KB, row stride 64 shorts
    __shared__ short BsF[2][128 * 64];
    int tid = threadIdx.x;
    int wave = tid >> 6, lane = tid & 63;
    int l16 = lane & 15, quad = lane >> 4;

    // ---- XCD swizzle ----
    int MT = M >> 7;              // number of 128-row m-tiles
    int full = MT >> 3;           // full 8-m-tile super-groups
    int bid = blockIdx.x;
    int h, mt;
    if (bid < (full << 6)) {
        int s = bid >> 6, r = bid & 63;
        h = r >> 3;
        mt = (s << 3) | (r & 7);
    } else {
        int r2 = bid - (full << 6);
        int rem = MT - (full << 3);
        h = r2 / rem;
        mt = (full << 3) + (r2 - h * rem);
    }
    bool isww = h < 4;
    int hh = isww ? h : h - 4;
    int bm = mt * 128, bn = h * 128;
    v4f acc[2][8] = {};

    int laneR = lane >> 3;                 // 0..7
    int laneC = (lane & 7) ^ laneR;        // swizzled 16B-chunk index
    const __hip_bfloat16* ga = A  + (size_t)(bm + wave * 32 + laneR) * K + laneC * 8;
    const __hip_bfloat16* gb = Bt + (size_t)(bn + wave * 32 + laneR) * K + laneC * 8;
    int lofs = (wave * 32) * 64;           // short offset of this wave's 32-row slab

    auto STAGE = [&](int buf, int k0) {
#pragma unroll
        for (int j = 0; j < 4; j++) {
            gl2lds16(ga + (size_t)(j * 8) * K + k0, &AsF[buf][lofs + j * 512]);
            gl2lds16(gb + (size_t)(j * 8) * K + k0, &BsF[buf][lofs + j * 512]);
        }
    };
    auto COMPUTE = [&](int buf) {
#pragma unroll
        for (int kh = 0; kh < 2; kh++) {
            int s = (kh * 4 + quad) ^ (l16 & 7);
            v8s a[2], b[8];
#pragma unroll
            for (int rr = 0; rr < 2; rr++)
                a[rr] = *(const v8s*)&AsF[buf][(wave * 32 + rr * 16 + l16) * 64 + s * 8];
#pragma unroll
            for (int c = 0; c < 8; c++)
                b[c] = *(const v8s*)&BsF[buf][(c * 16 + l16) * 64 + s * 8];
#pragma unroll
            for (int rr = 0; rr < 2; rr++)
#pragma unroll
                for (int c = 0; c < 8; c++)
                    acc[rr][c] = __builtin_amdgcn_mfma_f32_16x16x32_bf16(a[rr], b[c], acc[rr][c], 0, 0, 0);
        }
    };

    // prologue: fill buf 0 with k=0 (8 loads in flight)
    STAGE(0, 0);
    // main loop: 2 tiles per iteration, compile-time buffer indices.
    // K is a multiple of 128 here (256 or 128) -> tile count even.
    for (int k0 = 0; k0 < K; k0 += 128) {
        if (k0 + 64 < K) {
            STAGE(1, k0 + 64);                                   // +8 in flight
            asm volatile("s_waitcnt vmcnt(8)" ::: "memory");     // tile(k0) landed
        } else {
            asm volatile("s_waitcnt vmcnt(0)" ::: "memory");
        }
        __builtin_amdgcn_s_barrier();                            // all waves: buf0 valid
        asm volatile("" ::: "memory");
        COMPUTE(0);
        __builtin_amdgcn_s_barrier();                            // all waves done reading buf0
        asm volatile("" ::: "memory");
        if (k0 + 128 < K) {
            STAGE(0, k0 + 128);
            asm volatile("s_waitcnt vmcnt(8)" ::: "memory");     // tile(k0+64) landed
        } else {
            asm volatile("s_waitcnt vmcnt(0)" ::: "memory");
        }
        __builtin_amdgcn_s_barrier();                            // buf1 valid
        asm volatile("" ::: "memory");
        COMPUTE(1);
        __builtin_amdgcn_s_barrier();                            // done reading buf1
        asm volatile("" ::: "memory");
    }

    // ---- C writeback via LDS re-stage (buffers free now; wave-private slabs) ----
    // flat 32KB region = AsF; local C tile row-major [128][128] bf16.
    short* cs = &AsF[0][0];
#pragma unroll
    for (int rr = 0; rr < 2; rr++)
#pragma unroll
        for (int c = 0; c < 8; c++)
#pragma unroll
            for (int i = 0; i < 4; i++) {
                int lr = wave * 32 + rr * 16 + quad * 4 + i;
                cs[lr * 128 + c * 16 + l16] = (short)__bfloat16_as_ushort(__float2bfloat16(acc[rr][c][i]));
            }
    // read back coalesced: each lane 16B per row-group; 8 groups of 4 rows
    {
        short* Cs = (short*)C;
#pragma unroll
        for (int j = 0; j < 8; j++) {
            int lr = wave * 32 + j * 4 + (lane >> 4);     // local row
            int cc = (lane & 15) * 8;                     // 8 cols = 16B
            v8s val = *(const v8s*)&cs[lr * 128 + cc];
            *(v8s*)&Cs[(size_t)(bm + lr) * N + bn + cc] = val;
        }
    }
    // epilogue: el (and er for ww heads) via per-lane dot + 16-lane shuffle reduce
    const float* alp = isww ? al0 : al1;
    float* elp = isww ? el0 : el1;
    float* erp = isww ? er0 : nullptr;
    float alv[8], arv[8];
#pragma unroll
    for (int c = 0; c < 8; c++) {
        alv[c] = alp[hh * 128 + c * 16 + l16];
        arv[c] = isww ? ar0[hh * 128 + c * 16 + l16] : 0.f;
    }
#pragma unroll
    for (int rr = 0; rr < 2; rr++)
#pragma unroll
        for (int i = 0; i < 4; i++) {
            float pl = 0.f, pr = 0.f;
#pragma unroll
            for (int c = 0; c < 8; c++) {
                pl += acc[rr][c][i] * alv[c];
                pr += acc[rr][c][i] * arv[c];
            }
#pragma unroll
            for (int off = 1; off < 16; off <<= 1) {
                pl += __shfl_xor(pl, off);
                pr += __shfl_xor(pr, off);
            }
            if (l16 == 0) {
                int row = bm + wave * 32 + rr * 16 + quad * 4 + i;
                elp[(size_t)row * 4 + hh] = pl;
                if (erp) erp[(size_t)row * 4 + hh] = pr;
            }
        }
}

// ---------- CSR build ----------
__global__ void hist_k(const int* __restrict__ dst, int* __restrict__ deg, int E) {
    int t = blockIdx.x * blockDim.x + threadIdx.x;
    if (t < E) atomicAdd(&deg[dst[t]], 1);
}

// 3-phase exclusive scan: 1024 elems/block (256 thr x 4)
__global__ __launch_bounds__(256) void scan_block(const int* __restrict__ deg,
                                                  int* __restrict__ rp,
                                                  int* __restrict__ bsum, int N) {
    __shared__ int ts[256];
    int tid = threadIdx.x;
    int base = blockIdx.x * 1024 + tid * 4;
    int v0 = 0, v1 = 0, v2 = 0, v3 = 0;
    if (base + 3 < N) {
        int4 q = *(const int4*)(deg + base);
        v0 = q.x; v1 = q.y; v2 = q.z; v3 = q.w;
    } else {
        if (base + 0 < N) v0 = deg[base + 0];
        if (base + 1 < N) v1 = deg[base + 1];
        if (base + 2 < N) v2 = deg[base + 2];
        if (base + 3 < N) v3 = deg[base + 3];
    }
    int s = v0 + v1 + v2 + v3;
    ts[tid] = s;
    __syncthreads();
    for (int off = 1; off < 256; off <<= 1) {
        int t = (tid >= off) ? ts[tid - off] : 0;
        __syncthreads();
        ts[tid] += t;
        __syncthreads();
    }
    int excl = ts[tid] - s;
    if (tid == 255) bsum[blockIdx.x] = ts[255];
    if (base + 0 < N) rp[base + 0] = excl;
    if (base + 1 < N) rp[base + 1] = excl + v0;
    if (base + 2 < N) rp[base + 2] = excl + v0 + v1;
    if (base + 3 < N) rp[base + 3] = excl + v0 + v1 + v2;
}

__global__ __launch_bounds__(256) void scan_bsum(int* __restrict__ bsum, int nb) {
    __shared__ int ts[256];
    int tid = threadIdx.x;
    int v = (tid < nb) ? bsum[tid] : 0;
    ts[tid] = v;
    __syncthreads();
    for (int off = 1; off < 256; off <<= 1) {
        int t = (tid >= off) ? ts[tid - off] : 0;
        __syncthreads();
        ts[tid] += t;
        __syncthreads();
    }
    if (tid < nb) bsum[tid] = ts[tid] - v;
}

__global__ __launch_bounds__(256) void add_off(int* __restrict__ rp,
                                               const int* __restrict__ bsum,
                                               int N, int E) {
    int tid = threadIdx.x;
    int base = blockIdx.x * 1024 + tid * 4;
    int o = bsum[blockIdx.x];
    if (base + 3 < N) {
        int4 q = *(const int4*)(rp + base);
        q.x += o; q.y += o; q.z += o; q.w += o;
        *(int4*)(rp + base) = q;
    } else {
        if (base + 0 < N) rp[base + 0] += o;
        if (base + 1 < N) rp[base + 1] += o;
        if (base + 2 < N) rp[base + 2] += o;
        if (base + 3 < N) rp[base + 3] += o;
    }
    if (blockIdx.x == 0 && tid == 0) rp[N] = E;
}

__global__ void scatter_edges(const int* __restrict__ src, const int* __restrict__ dst,
                              const int* __restrict__ rp, int* __restrict__ cnt,
                              int* __restrict__ ss, int E) {
    int t = blockIdx.x * blockDim.x + threadIdx.x;
    if (t >= E) return;
    int d = dst[t];
    int pos = rp[d] + atomicAdd(&cnt[d], 1);
    ss[pos] = src[t];
}

// ---------- fused edge-softmax + aggregate: one wave per dst ----------
// Online softmax per (dst,head); depth-2 software pipeline: the src index is
// prefetched two edges ahead and the el / z-row loads for edge i+1 are ISSUED
// before edge i's accumulation, so each edge's load latency is hidden behind
// the previous edge's math + the load-queue slack.
__global__ __launch_bounds__(256) void softmax_agg(const int* __restrict__ rp,
                                                   const int* __restrict__ ss,
                                                   const float* __restrict__ el,
                                                   const float* __restrict__ er,
                                                   const __hip_bfloat16* __restrict__ z,
                                                   int zoff,
                                                   const float* __restrict__ b,
                                                   float* __restrict__ outf,
                                                   __hip_bfloat16* __restrict__ outb,
                                                   int Nd) {
    int wave = threadIdx.x >> 6, lane = threadIdx.x & 63;
    int d = blockIdx.x * 4 + wave;
    if (d >= Nd) return;
    int i0 = rp[d], i1 = rp[d + 1];
    float4 erd = *(const float4*)(er + (size_t)d * 4);
    float m[4], l[4], accx[4], accy[4];
#pragma unroll
    for (int h = 0; h < 4; h++) { m[h] = -FLT_MAX; l[h] = 0.f; accx[h] = 0.f; accy[h] = 0.f; }

    int sB = 0;
    float4 eA = make_float4(0.f, 0.f, 0.f, 0.f);
    unsigned uA0 = 0, uA1 = 0, uA2 = 0, uA3 = 0;
    if (i0 < i1) {
        int sA = ss[i0];
        sB = (i0 + 1 < i1) ? ss[i0 + 1] : sA;
        eA = *(const float4*)(el + (size_t)sA * 4);
        const unsigned* zr = (const unsigned*)(z + (size_t)sA * 1024 + zoff);
        uA0 = zr[lane]; uA1 = zr[64 + lane]; uA2 = zr[128 + lane]; uA3 = zr[192 + lane];
    }
    for (int i = i0; i < i1; i++) {
        int sC = (i + 2 < i1) ? ss[i + 2] : sB;          // prefetch src idx 2 ahead
        float4 eB = *(const float4*)(el + (size_t)sB * 4);  // issue next-edge loads now
        const unsigned* zrB = (const unsigned*)(z + (size_t)sB * 1024 + zoff);
        unsigned uB0 = zrB[lane], uB1 = zrB[64 + lane], uB2 = zrB[128 + lane], uB3 = zrB[192 + lane];

        unsigned u[4] = {uA0, uA1, uA2, uA3};
        float e[4] = {eA.x + erd.x, eA.y + erd.y, eA.z + erd.z, eA.w + erd.w};
#pragma unroll
        for (int h = 0; h < 4; h++) {
            float eh = e[h] > 0.f ? e[h] : 0.2f * e[h];   // leaky_relu(0.2)
            float nm = fmaxf(m[h], eh);
            float sc = __expf(m[h] - nm);
            float p  = __expf(eh - nm);
            m[h] = nm;
            l[h] = l[h] * sc + p;
            accx[h] = accx[h] * sc + p * blo(u[h]);
            accy[h] = accy[h] * sc + p * bhi(u[h]);
        }
        eA = eB; uA0 = uB0; uA1 = uB1; uA2 = uB2; uA3 = uB3;
        sB = sC;
    }
    int f = lane * 2;
    float ax = b[f] + b[128 + f] + b[256 + f] + b[384 + f];
    float ay = b[f + 1] + b[129 + f] + b[257 + f] + b[385 + f];
#pragma unroll
    for (int h = 0; h < 4; h++) {
        float inv = l[h] > 0.f ? 1.f / l[h] : 0.f;
        ax += accx[h] * inv;
        ay += accy[h] * inv;
    }
    ax = fmaxf(ax, 0.f);
    ay = fmaxf(ay, 0.f);
    if (outf) {
        *(float2*)(outf + (size_t)d * 128 + f) = make_float2(ax, ay);
    } else {
        __hip_bfloat162 p2;
        p2.x = __float2bfloat16(ax);
        p2.y = __float2bfloat16(ay);
        *(__hip_bfloat162*)(outb + (size_t)d * 128 + f) = p2;
    }
}

static inline char* aln(char*& p, size_t bytes) {
    char* r = p;
    p += (bytes + 255) & ~(size_t)255;
    return r;
}

static void build_csr(const int* src, const int* dst, int Nd, int E,
                      int* rp, int* deg, int* bsum, int* ss, hipStream_t stream) {
    hipMemsetAsync(deg, 0, (size_t)Nd * 2 * 4, stream);
    hist_k<<<(E + 255) / 256, 256, 0, stream>>>(dst, deg, E);
    int nb = (Nd + 1023) / 1024;
    scan_block<<<nb, 256, 0, stream>>>(deg, rp, bsum, Nd);
    scan_bsum<<<1, 256, 0, stream>>>(bsum, nb);
    add_off<<<nb, 256, 0, stream>>>(rp, bsum, Nd, E);
    scatter_edges<<<(E + 255) / 256, 256, 0, stream>>>(src, dst, rp, deg + Nd, ss, E);
}

extern "C" void kernel_launch(void* const* d_in, const int* in_sizes, int n_in,
                              void* d_out, int out_size, void* d_ws, size_t ws_size,
                              hipStream_t stream) {
    const float* xw     = (const float*)d_in[0];
    const float* xd     = (const float*)d_in[1];
    const float* W_ww0  = (const float*)d_in[2];
    const float* al_ww0 = (const float*)d_in[3];
    const float* ar_ww0 = (const float*)d_in[4];
    const float* b_ww0  = (const float*)d_in[5];
    const float* W_wd0  = (const float*)d_in[6];
    const float* al_wd0 = (const float*)d_in[7];
    const float* ar_wd0 = (const float*)d_in[8];
    const float* b_wd0  = (const float*)d_in[9];
    const float* W_ww1  = (const float*)d_in[10];
    const float* al_ww1 = (const float*)d_in[11];
    const float* ar_ww1 = (const float*)d_in[12];
    const float* b_ww1  = (const float*)d_in[13];
    const float* W_wd1  = (const float*)d_in[14];
    const float* al_wd1 = (const float*)d_in[15];
    const float* ar_wd1 = (const float*)d_in[16];
    const float* b_wd1  = (const float*)d_in[17];
    const int* ww_src   = (const int*)d_in[18];
    const int* ww_dst   = (const int*)d_in[19];
    const int* wd_src   = (const int*)d_in[20];
    const int* wd_dst   = (const int*)d_in[21];

    // ---- workspace carve ----
    char* p = (char*)d_ws;
    __hip_bfloat16* z    = (__hip_bfloat16*)aln(p, (size_t)NW * 1024 * 2);  // 164 MB
    __hip_bfloat16* xwb  = (__hip_bfloat16*)aln(p, (size_t)NW * 256 * 2);
    __hip_bfloat16* xw1b = (__hip_bfloat16*)aln(p, (size_t)NW * 128 * 2);
    __hip_bfloat16* xd1b = (__hip_bfloat16*)aln(p, (size_t)ND * 128 * 2);
    __hip_bfloat16* Wt   = (__hip_bfloat16*)aln(p, (size_t)1024 * 256 * 2);
    float* el0  = (float*)aln(p, (size_t)NW * 4 * 4);   // ww src logits
    float* er0  = (float*)aln(p, (size_t)NW * 4 * 4);   // ww dst logits
    float* el1  = (float*)aln(p, (size_t)NW * 4 * 4);   // wd src logits (word rows)
    float* er1  = (float*)aln(p, (size_t)ND * 4 * 4);   // wd dst logits (doc rows)
    float* Wr   = (float*)aln(p, 4096);
    // CSR ww
    int* rp_ww  = (int*)aln(p, (size_t)(NW + 1) * 4);
    int* deg_ww = (int*)aln(p, (size_t)NW * 2 * 4);   // deg + cnt, one memset
    int* ss_ww  = (int*)aln(p, (size_t)EWW * 4);
    // CSR wd
    int* rp_wd  = (int*)aln(p, (size_t)(ND + 1) * 4);
    int* deg_wd = (int*)aln(p, (size_t)ND * 2 * 4);
    int* ss_wd  = (int*)aln(p, (size_t)EWD * 4);
    int* bsum   = (int*)aln(p, 1024);

    float* out_xw = (float*)d_out;
    float* out_xd = out_xw + (size_t)NW * 128;

    // ---- cast input features ----
    cast_bf16_v4<<<(NW * 256 / 4 + 255) / 256, 256, 0, stream>>>(
        (const float4*)xw, (uint2*)xwb, NW * 256 / 4);

    // ---- CSR build (once per graph, reused by both layers) ----
    build_csr(ww_src, ww_dst, NW, EWW, rp_ww, deg_ww, bsum, ss_ww, stream);
    build_csr(wd_src, wd_dst, ND, EWD, rp_wd, deg_wd, bsum, ss_wd, stream);

    const int GEMM_BLOCKS = 8 * (NW / 128);   // 5000

    // ================= layer 0 (K=256) =================
    transpose_w2<<<(1024 * 256 + 255) / 256, 256, 0, stream>>>(W_ww0, W_wd0, Wt, 256);
    gemm_epi<<<GEMM_BLOCKS, 256, 0, stream>>>(xwb, Wt, z, al_ww0, ar_ww0, al_wd0,
                                              el0, er0, el1, NW, 256);
    make_wr<<<(256 * 4 + 255) / 256, 256, 0, stream>>>(W_wd0, ar_wd0, Wr, 256);
    attn_f32<<<(ND + 3) / 4, 256, 0, stream>>>(xd, Wr, er1, ND, 256);
    softmax_agg<<<(NW + 3) / 4, 256, 0, stream>>>(rp_ww, ss_ww, el0, er0, z, 0,
                                                  b_ww0, nullptr, xw1b, NW);
    softmax_agg<<<(ND + 3) / 4, 256, 0, stream>>>(rp_wd, ss_wd, el1, er1, z, 512,
                                                  b_wd0, nullptr, xd1b, ND);

    // ================= layer 1 (K=128) =================
    transpose_w2<<<(1024 * 128 + 255) / 256, 256, 0, stream>>>(W_ww1, W_wd1, Wt, 128);
    gemm_epi<<<GEMM_BLOCKS, 256, 0, stream>>>(xw1b, Wt, z, al_ww1, ar_ww1, al_wd1,
                                              el0, er0, el1, NW, 128);
    make_wr<<<(128 * 4 + 255) / 256, 256, 0, stream>>>(W_wd1, ar_wd1, Wr, 128);
    attn_bf16<<<(ND + 3) / 4, 256, 0, stream>>>(xd1b, Wr, er1, ND, 128);
    softmax_agg<<<(NW + 3) / 4, 256, 0, stream>>>(rp_ww, ss_ww, el0, er0, z, 0,
                                                  b_ww1, out_xw, nullptr, NW);
    softmax_agg<<<(ND + 3) / 4, 256, 0, stream>>>(rp_wd, ss_wd, el1, er1, z, 512,
                                                  b_wd1, out_xd, nullptr, ND);
}

// Round 4
// 569.302 us; speedup vs baseline: 1.1047x; 1.0749x over previous
//
#include <hip/hip_runtime.h>
#include <hip/hip_bf16.h>
#include <cstddef>
#include <cfloat>

#define NW 80000
#define ND 16000
#define EWW 200000
#define EWD 200000

typedef short v8s __attribute__((ext_vector_type(8)));
typedef float v4f __attribute__((ext_vector_type(4)));

static __device__ __forceinline__ float blo(unsigned u) { return __uint_as_float(u << 16); }
static __device__ __forceinline__ float bhi(unsigned u) { return __uint_as_float(u & 0xffff0000u); }

// async global->LDS 16B copy: lane i of the wave writes lds_base + i*16
static __device__ __forceinline__ void gl2lds16(const void* g, void* l) {
    __builtin_amdgcn_global_load_lds((__attribute__((address_space(1))) void*)g,
                                     (__attribute__((address_space(3))) void*)l, 16, 0, 0);
}

// ---------- fp32 -> bf16 cast, x4 vectorized ----------
__global__ void cast_bf16_v4(const float4* __restrict__ x, uint2* __restrict__ xb, int n4) {
    int i = blockIdx.x * blockDim.x + threadIdx.x;
    if (i >= n4) return;
    float4 v = x[i];
    __hip_bfloat162 a, b;
    a.x = __float2bfloat16(v.x); a.y = __float2bfloat16(v.y);
    b.x = __float2bfloat16(v.z); b.y = __float2bfloat16(v.w);
    uint2 o;
    o.x = *(unsigned*)&a; o.y = *(unsigned*)&b;
    xb[i] = o;
}

// ---------- [Wa | Wb] ([K,512] each) -> Wt[1024,K] bf16 ----------
__global__ void transpose_w2(const float* __restrict__ Wa, const float* __restrict__ Wb,
                             __hip_bfloat16* __restrict__ Wt, int K) {
    int i = blockIdx.x * blockDim.x + threadIdx.x;
    if (i >= 1024 * K) return;
    int n = i / K, k = i - n * K;
    float v = (n < 512) ? Wa[k * 512 + n] : Wb[k * 512 + (n - 512)];
    Wt[i] = __float2bfloat16(v);
}

// ---------- Wr = per-head contraction of W with ar: [K,4] (dst side of wd) ----------
__global__ void make_wr(const float* __restrict__ W, const float* __restrict__ ar,
                        float* __restrict__ Wr, int K) {
    int i = blockIdx.x * blockDim.x + threadIdx.x;
    if (i >= K * 4) return;
    int k = i >> 2, h = i & 3;
    float sr = 0.f;
    const float* wr = W + (size_t)k * 512 + h * 128;
    const float* arr = ar + h * 128;
    for (int f = 0; f < 128; f++) sr += wr[f] * arr[f];
    Wr[k * 4 + h] = sr;
}

// ---------- er = x @ Wr ([N,4]); one wave per row; fp32 x ----------
__global__ __launch_bounds__(256) void attn_f32(const float* __restrict__ x,
                                                const float* __restrict__ Wv,
                                                float* __restrict__ out, int N, int K) {
    int wave = threadIdx.x >> 6, lane = threadIdx.x & 63;
    int row = blockIdx.x * 4 + wave;
    if (row >= N) return;
    const float* xr = x + (size_t)row * K;
    float a0 = 0.f, a1 = 0.f, a2 = 0.f, a3 = 0.f;
    for (int k = lane; k < K; k += 64) {
        float v = xr[k];
        const float* w = Wv + k * 4;
        a0 += v * w[0]; a1 += v * w[1]; a2 += v * w[2]; a3 += v * w[3];
    }
#pragma unroll
    for (int off = 32; off; off >>= 1) {
        a0 += __shfl_down(a0, off); a1 += __shfl_down(a1, off);
        a2 += __shfl_down(a2, off); a3 += __shfl_down(a3, off);
    }
    if (lane == 0) {
        out[row * 4 + 0] = a0; out[row * 4 + 1] = a1;
        out[row * 4 + 2] = a2; out[row * 4 + 3] = a3;
    }
}

// ---------- bf16-x variant ----------
__global__ __launch_bounds__(256) void attn_bf16(const __hip_bfloat16* __restrict__ x,
                                                 const float* __restrict__ Wv,
                                                 float* __restrict__ out, int N, int K) {
    int wave = threadIdx.x >> 6, lane = threadIdx.x & 63;
    int row = blockIdx.x * 4 + wave;
    if (row >= N) return;
    const __hip_bfloat16* xr = x + (size_t)row * K;
    float a0 = 0.f, a1 = 0.f, a2 = 0.f, a3 = 0.f;
    for (int k = lane; k < K; k += 64) {
        float v = __bfloat162float(xr[k]);
        const float* w = Wv + k * 4;
        a0 += v * w[0]; a1 += v * w[1]; a2 += v * w[2]; a3 += v * w[3];
    }
#pragma unroll
    for (int off = 32; off; off >>= 1) {
        a0 += __shfl_down(a0, off); a1 += __shfl_down(a1, off);
        a2 += __shfl_down(a2, off); a3 += __shfl_down(a3, off);
    }
    if (lane == 0) {
        out[row * 4 + 0] = a0; out[row * 4 + 1] = a1;
        out[row * 4 + 2] = a2; out[row * 4 + 3] = a3;
    }
}

// ---------- merged bf16 MFMA GEMM (both relations) + attention-logit epilogue ----------
// z[M,1024] = A[M,K] @ [W_ww | W_wd]  (Bt = concat^T [1024,K]).  BM=128, BK=64.
// T3+T4: double-buffered LDS, raw s_barrier + counted vmcnt(8) so next tile's
// 8 global_load_lds stay in flight across the barrier.
// C writeback re-staged via LDS with per-4-row chunk ROTATION (chunk += 2*(lr>>2),
// bijective within each row) so the 4 quads of a store hit 8 distinct bank-groups
// (r2 measured 2.56M conflict cycles with the linear layout).
__global__ __launch_bounds__(256) void gemm_epi(const __hip_bfloat16* __restrict__ A,
                                                const __hip_bfloat16* __restrict__ Bt,
                                                __hip_bfloat16* __restrict__ C,
                                                const float* __restrict__ al0,
                                                const float* __restrict__ ar0,
                                                const float* __restrict__ al1,
                                                float* __restrict__ el0,
                                                float* __restrict__ er0,
                                                float* __restrict__ el1,
                                                int M, int K) {
    const int N = 1024;
    __shared__ short AsF[2][128 * 64];   // 2 x 16 KB, row stride 64 shorts
    __shared__ short BsF[2][128 * 64];
    int tid = threadIdx.x;
    int wave = tid >> 6, lane = tid & 63;
    int l16 = lane & 15, quad = lane >> 4;

    // ---- XCD swizzle ----
    int MT = M >> 7;              // number of 128-row m-tiles
    int full = MT >> 3;           // full 8-m-tile super-groups
    int bid = blockIdx.x;
    int h, mt;
    if (bid < (full << 6)) {
        int s = bid >> 6, r = bid & 63;
        h = r >> 3;
        mt = (s << 3) | (r & 7);
    } else {
        int r2 = bid - (full << 6);
        int rem = MT - (full << 3);
        h = r2 / rem;
        mt = (full << 3) + (r2 - h * rem);
    }
    bool isww = h < 4;
    int hh = isww ? h : h - 4;
    int bm = mt * 128, bn = h * 128;
    v4f acc[2][8] = {};

    int laneR = lane >> 3;                 // 0..7
    int laneC = (lane & 7) ^ laneR;        // swizzled 16B-chunk index
    const __hip_bfloat16* ga = A  + (size_t)(bm + wave * 32 + laneR) * K + laneC * 8;
    const __hip_bfloat16* gb = Bt + (size_t)(bn + wave * 32 + laneR) * K + laneC * 8;
    int lofs = (wave * 32) * 64;           // short offset of this wave's 32-row slab

    auto STAGE = [&](int buf, int k0) {
#pragma unroll
        for (int j = 0; j < 4; j++) {
            gl2lds16(ga + (size_t)(j * 8) * K + k0, &AsF[buf][lofs + j * 512]);
            gl2lds16(gb + (size_t)(j * 8) * K + k0, &BsF[buf][lofs + j * 512]);
        }
    };
    auto COMPUTE = [&](int buf) {
#pragma unroll
        for (int kh = 0; kh < 2; kh++) {
            int s = (kh * 4 + quad) ^ (l16 & 7);
            v8s a[2], b[8];
#pragma unroll
            for (int rr = 0; rr < 2; rr++)
                a[rr] = *(const v8s*)&AsF[buf][(wave * 32 + rr * 16 + l16) * 64 + s * 8];
#pragma unroll
            for (int c = 0; c < 8; c++)
                b[c] = *(const v8s*)&BsF[buf][(c * 16 + l16) * 64 + s * 8];
#pragma unroll
            for (int rr = 0; rr < 2; rr++)
#pragma unroll
                for (int c = 0; c < 8; c++)
                    acc[rr][c] = __builtin_amdgcn_mfma_f32_16x16x32_bf16(a[rr], b[c], acc[rr][c], 0, 0, 0);
        }
    };

    // prologue: fill buf 0 with k=0 (8 loads in flight)
    STAGE(0, 0);
    // main loop: 2 tiles per iteration, compile-time buffer indices.
    // K is a multiple of 128 here (256 or 128) -> tile count even.
    for (int k0 = 0; k0 < K; k0 += 128) {
        if (k0 + 64 < K) {
            STAGE(1, k0 + 64);                                   // +8 in flight
            asm volatile("s_waitcnt vmcnt(8)" ::: "memory");     // tile(k0) landed
        } else {
            asm volatile("s_waitcnt vmcnt(0)" ::: "memory");
        }
        __builtin_amdgcn_s_barrier();                            // all waves: buf0 valid
        asm volatile("" ::: "memory");
        COMPUTE(0);
        __builtin_amdgcn_s_barrier();                            // all waves done reading buf0
        asm volatile("" ::: "memory");
        if (k0 + 128 < K) {
            STAGE(0, k0 + 128);
            asm volatile("s_waitcnt vmcnt(8)" ::: "memory");     // tile(k0+64) landed
        } else {
            asm volatile("s_waitcnt vmcnt(0)" ::: "memory");
        }
        __builtin_amdgcn_s_barrier();                            // buf1 valid
        asm volatile("" ::: "memory");
        COMPUTE(1);
        __builtin_amdgcn_s_barrier();                            // done reading buf1
        asm volatile("" ::: "memory");
    }

    // ---- C writeback via LDS re-stage (buffers free now; wave-private slabs) ----
    // flat 32KB region = AsF; local C tile [128][128] bf16 with rotated chunks.
    short* cs = &AsF[0][0];
#pragma unroll
    for (int rr = 0; rr < 2; rr++)
#pragma unroll
        for (int c = 0; c < 8; c++)
#pragma unroll
            for (int i = 0; i < 4; i++) {
                int lr = wave * 32 + rr * 16 + quad * 4 + i;
                int sIdx = c * 16 + l16;
                int chunk = ((sIdx >> 3) + 2 * (lr >> 2)) & 15;   // rotate per 4-row group
                cs[lr * 128 + (chunk << 3) + (sIdx & 7)] =
                    (short)__bfloat16_as_ushort(__float2bfloat16(acc[rr][c][i]));
            }
    // read back coalesced: each lane 16B per row-group; 8 groups of 4 rows
    {
        short* Cs = (short*)C;
#pragma unroll
        for (int j = 0; j < 8; j++) {
            int lr = wave * 32 + j * 4 + (lane >> 4);     // local row
            int cc = lane & 15;                           // logical 16B chunk
            int chunk = (cc + 2 * (lr >> 2)) & 15;        // physical chunk
            v8s val = *(const v8s*)&cs[lr * 128 + (chunk << 3)];
            *(v8s*)&Cs[(size_t)(bm + lr) * N + bn + cc * 8] = val;
        }
    }
    // epilogue: el (and er for ww heads) via per-lane dot + 16-lane shuffle reduce
    const float* alp = isww ? al0 : al1;
    float* elp = isww ? el0 : el1;
    float* erp = isww ? er0 : nullptr;
    float alv[8], arv[8];
#pragma unroll
    for (int c = 0; c < 8; c++) {
        alv[c] = alp[hh * 128 + c * 16 + l16];
        arv[c] = isww ? ar0[hh * 128 + c * 16 + l16] : 0.f;
    }
#pragma unroll
    for (int rr = 0; rr < 2; rr++)
#pragma unroll
        for (int i = 0; i < 4; i++) {
            float pl = 0.f, pr = 0.f;
#pragma unroll
            for (int c = 0; c < 8; c++) {
                pl += acc[rr][c][i] * alv[c];
                pr += acc[rr][c][i] * arv[c];
            }
#pragma unroll
            for (int off = 1; off < 16; off <<= 1) {
                pl += __shfl_xor(pl, off);
                pr += __shfl_xor(pr, off);
            }
            if (l16 == 0) {
                int row = bm + wave * 32 + rr * 16 + quad * 4 + i;
                elp[(size_t)row * 4 + hh] = pl;
                if (erp) erp[(size_t)row * 4 + hh] = pr;
            }
        }
}

// ---------- CSR build ----------
__global__ void hist_k(const int* __restrict__ dst, int* __restrict__ deg, int E) {
    int t = blockIdx.x * blockDim.x + threadIdx.x;
    if (t < E) atomicAdd(&deg[dst[t]], 1);
}

// 3-phase exclusive scan: 1024 elems/block (256 thr x 4)
__global__ __launch_bounds__(256) void scan_block(const int* __restrict__ deg,
                                                  int* __restrict__ rp,
                                                  int* __restrict__ bsum, int N) {
    __shared__ int ts[256];
    int tid = threadIdx.x;
    int base = blockIdx.x * 1024 + tid * 4;
    int v0 = 0, v1 = 0, v2 = 0, v3 = 0;
    if (base + 3 < N) {
        int4 q = *(const int4*)(deg + base);
        v0 = q.x; v1 = q.y; v2 = q.z; v3 = q.w;
    } else {
        if (base + 0 < N) v0 = deg[base + 0];
        if (base + 1 < N) v1 = deg[base + 1];
        if (base + 2 < N) v2 = deg[base + 2];
        if (base + 3 < N) v3 = deg[base + 3];
    }
    int s = v0 + v1 + v2 + v3;
    ts[tid] = s;
    __syncthreads();
    for (int off = 1; off < 256; off <<= 1) {
        int t = (tid >= off) ? ts[tid - off] : 0;
        __syncthreads();
        ts[tid] += t;
        __syncthreads();
    }
    int excl = ts[tid] - s;
    if (tid == 255) bsum[blockIdx.x] = ts[255];
    if (base + 0 < N) rp[base + 0] = excl;
    if (base + 1 < N) rp[base + 1] = excl + v0;
    if (base + 2 < N) rp[base + 2] = excl + v0 + v1;
    if (base + 3 < N) rp[base + 3] = excl + v0 + v1 + v2;
}

__global__ __launch_bounds__(256) void scan_bsum(int* __restrict__ bsum, int nb) {
    __shared__ int ts[256];
    int tid = threadIdx.x;
    int v = (tid < nb) ? bsum[tid] : 0;
    ts[tid] = v;
    __syncthreads();
    for (int off = 1; off < 256; off <<= 1) {
        int t = (tid >= off) ? ts[tid - off] : 0;
        __syncthreads();
        ts[tid] += t;
        __syncthreads();
    }
    if (tid < nb) bsum[tid] = ts[tid] - v;
}

__global__ __launch_bounds__(256) void add_off(int* __restrict__ rp,
                                               const int* __restrict__ bsum,
                                               int N, int E) {
    int tid = threadIdx.x;
    int base = blockIdx.x * 1024 + tid * 4;
    int o = bsum[blockIdx.x];
    if (base + 3 < N) {
        int4 q = *(const int4*)(rp + base);
        q.x += o; q.y += o; q.z += o; q.w += o;
        *(int4*)(rp + base) = q;
    } else {
        if (base + 0 < N) rp[base + 0] += o;
        if (base + 1 < N) rp[base + 1] += o;
        if (base + 2 < N) rp[base + 2] += o;
        if (base + 3 < N) rp[base + 3] += o;
    }
    if (blockIdx.x == 0 && tid == 0) rp[N] = E;
}

__global__ void scatter_edges(const int* __restrict__ src, const int* __restrict__ dst,
                              const int* __restrict__ rp, int* __restrict__ cnt,
                              int* __restrict__ ss, int E) {
    int t = blockIdx.x * blockDim.x + threadIdx.x;
    if (t >= E) return;
    int d = dst[t];
    int pos = rp[d] + atomicAdd(&cnt[d], 1);
    ss[pos] = src[t];
}

// ---------- fused edge-softmax + aggregate, BOTH relations in one dispatch ----------
// One wave per dst. Per-lane OWN-HEAD layout: lane covers 8 consecutive bf16 cols
// of head (lane>>4) via ONE dwordx4 per edge (was 4 stride-256B dwords + all-heads
// redundant math). Online softmax state (m,l) kept per-lane for its head only;
// cross-head sum + bias done once at the end with 2 shfl_xor steps.
// Edges processed in chunks of 4: all 4 ss indices -> all 4 (el,z) loads issued
// together (4KB in flight), next chunk's ss prefetched before current math.
__global__ __launch_bounds__(256) void softmax_agg2(
        const int* __restrict__ rp_w, const int* __restrict__ ss_w,
        const float* __restrict__ el_w, const float* __restrict__ er_w,
        const float* __restrict__ b_w,
        const int* __restrict__ rp_d, const int* __restrict__ ss_d,
        const float* __restrict__ el_d, const float* __restrict__ er_d,
        const float* __restrict__ b_d,
        const __hip_bfloat16* __restrict__ z,
        float* __restrict__ outf_w, __hip_bfloat16* __restrict__ outb_w,
        float* __restrict__ outf_d, __hip_bfloat16* __restrict__ outb_d,
        int nbw) {
    int wave = threadIdx.x >> 6, lane = threadIdx.x & 63;
    int h0 = lane >> 4, l16 = lane & 15;
    const int *rp, *ss;
    const float *el, *er, *bv;
    float* outf;
    __hip_bfloat16* outb;
    int d, Nd, zoff;
    if ((int)blockIdx.x < nbw) {
        rp = rp_w; ss = ss_w; el = el_w; er = er_w; bv = b_w;
        outf = outf_w; outb = outb_w; zoff = 0; Nd = NW;
        d = blockIdx.x * 4 + wave;
    } else {
        rp = rp_d; ss = ss_d; el = el_d; er = er_d; bv = b_d;
        outf = outf_d; outb = outb_d; zoff = 512; Nd = ND;
        d = (blockIdx.x - nbw) * 4 + wave;
    }
    if (d >= Nd) return;
    int i0 = rp[d], i1 = rp[d + 1];
    float er_own = er[(size_t)d * 4 + h0];
    float bb[8];
#pragma unroll
    for (int t = 0; t < 8; t++) bb[t] = bv[h0 * 128 + l16 * 8 + t];

    float m = -FLT_MAX, l = 0.f;
    float acc[8];
#pragma unroll
    for (int t = 0; t < 8; t++) acc[t] = 0.f;

    const __hip_bfloat16* zb = z + zoff;
    auto PROC = [&](float elv, const uint4& zv) {
        float e = elv + er_own;
        e = e > 0.f ? e : 0.2f * e;                 // leaky_relu(0.2)
        float nm = fmaxf(m, e);
        float sc = __expf(m - nm);
        float p  = __expf(e - nm);
        m = nm;
        l = l * sc + p;
        acc[0] = acc[0] * sc + p * blo(zv.x);
        acc[1] = acc[1] * sc + p * bhi(zv.x);
        acc[2] = acc[2] * sc + p * blo(zv.y);
        acc[3] = acc[3] * sc + p * bhi(zv.y);
        acc[4] = acc[4] * sc + p * blo(zv.z);
        acc[5] = acc[5] * sc + p * bhi(zv.z);
        acc[6] = acc[6] * sc + p * blo(zv.w);
        acc[7] = acc[7] * sc + p * bhi(zv.w);
    };

    if (i0 < i1) {
        int last = i1 - 1;
        int s0 = ss[i0];
        int s1 = ss[min(i0 + 1, last)];
        int s2 = ss[min(i0 + 2, last)];
        int s3 = ss[min(i0 + 3, last)];
        for (int i = i0; i < i1; i += 4) {
            // issue all of this chunk's data loads
            float e0 = el[(size_t)s0 * 4 + h0];
            float e1 = el[(size_t)s1 * 4 + h0];
            float e2 = el[(size_t)s2 * 4 + h0];
            float e3 = el[(size_t)s3 * 4 + h0];
            uint4 z0 = ((const uint4*)(zb + (size_t)s0 * 1024))[lane];
            uint4 z1 = ((const uint4*)(zb + (size_t)s1 * 1024))[lane];
            uint4 z2 = ((const uint4*)(zb + (size_t)s2 * 1024))[lane];
            uint4 z3 = ((const uint4*)(zb + (size_t)s3 * 1024))[lane];
            // prefetch next chunk's src indices (clamped; harmless dups)
            s0 = ss[min(i + 4, last)];
            s1 = ss[min(i + 5, last)];
            s2 = ss[min(i + 6, last)];
            s3 = ss[min(i + 7, last)];
            int rem = i1 - i;
            PROC(e0, z0);
            if (rem > 1) PROC(e1, z1);
            if (rem > 2) PROC(e2, z2);
            if (rem > 3) PROC(e3, z3);
        }
    }

    float inv = l > 0.f ? 1.f / l : 0.f;
    float v[8];
#pragma unroll
    for (int t = 0; t < 8; t++) v[t] = acc[t] * inv + bb[t];
    // sum the 4 head-groups (lanes g*16+j hold head g, cols 8j..8j+7)
#pragma unroll
    for (int t = 0; t < 8; t++) {
        v[t] += __shfl_xor(v[t], 16);
        v[t] += __shfl_xor(v[t], 32);
    }
#pragma unroll
    for (int t = 0; t < 8; t++) v[t] = fmaxf(v[t], 0.f);   // relu
    if (lane < 16) {
        if (outf) {
            float4 o0 = make_float4(v[0], v[1], v[2], v[3]);
            float4 o1 = make_float4(v[4], v[5], v[6], v[7]);
            *(float4*)(outf + (size_t)d * 128 + l16 * 8)     = o0;
            *(float4*)(outf + (size_t)d * 128 + l16 * 8 + 4) = o1;
        } else {
            __hip_bfloat162 p01, p23, p45, p67;
            p01.x = __float2bfloat16(v[0]); p01.y = __float2bfloat16(v[1]);
            p23.x = __float2bfloat16(v[2]); p23.y = __float2bfloat16(v[3]);
            p45.x = __float2bfloat16(v[4]); p45.y = __float2bfloat16(v[5]);
            p67.x = __float2bfloat16(v[6]); p67.y = __float2bfloat16(v[7]);
            uint4 o;
            o.x = *(unsigned*)&p01; o.y = *(unsigned*)&p23;
            o.z = *(unsigned*)&p45; o.w = *(unsigned*)&p67;
            *(uint4*)(outb + (size_t)d * 128 + l16 * 8) = o;
        }
    }
}

static inline char* aln(char*& p, size_t bytes) {
    char* r = p;
    p += (bytes + 255) & ~(size_t)255;
    return r;
}

static void build_csr(const int* src, const int* dst, int Nd, int E,
                      int* rp, int* deg, int* bsum, int* ss, hipStream_t stream) {
    hipMemsetAsync(deg, 0, (size_t)Nd * 2 * 4, stream);
    hist_k<<<(E + 255) / 256, 256, 0, stream>>>(dst, deg, E);
    int nb = (Nd + 1023) / 1024;
    scan_block<<<nb, 256, 0, stream>>>(deg, rp, bsum, Nd);
    scan_bsum<<<1, 256, 0, stream>>>(bsum, nb);
    add_off<<<nb, 256, 0, stream>>>(rp, bsum, Nd, E);
    scatter_edges<<<(E + 255) / 256, 256, 0, stream>>>(src, dst, rp, deg + Nd, ss, E);
}

extern "C" void kernel_launch(void* const* d_in, const int* in_sizes, int n_in,
                              void* d_out, int out_size, void* d_ws, size_t ws_size,
                              hipStream_t stream) {
    const float* xw     = (const float*)d_in[0];
    const float* xd     = (const float*)d_in[1];
    const float* W_ww0  = (const float*)d_in[2];
    const float* al_ww0 = (const float*)d_in[3];
    const float* ar_ww0 = (const float*)d_in[4];
    const float* b_ww0  = (const float*)d_in[5];
    const float* W_wd0  = (const float*)d_in[6];
    const float* al_wd0 = (const float*)d_in[7];
    const float* ar_wd0 = (const float*)d_in[8];
    const float* b_wd0  = (const float*)d_in[9];
    const float* W_ww1  = (const float*)d_in[10];
    const float* al_ww1 = (const float*)d_in[11];
    const float* ar_ww1 = (const float*)d_in[12];
    const float* b_ww1  = (const float*)d_in[13];
    const float* W_wd1  = (const float*)d_in[14];
    const float* al_wd1 = (const float*)d_in[15];
    const float* ar_wd1 = (const float*)d_in[16];
    const float* b_wd1  = (const float*)d_in[17];
    const int* ww_src   = (const int*)d_in[18];
    const int* ww_dst   = (const int*)d_in[19];
    const int* wd_src   = (const int*)d_in[20];
    const int* wd_dst   = (const int*)d_in[21];

    // ---- workspace carve ----
    char* p = (char*)d_ws;
    __hip_bfloat16* z    = (__hip_bfloat16*)aln(p, (size_t)NW * 1024 * 2);  // 164 MB
    __hip_bfloat16* xwb  = (__hip_bfloat16*)aln(p, (size_t)NW * 256 * 2);
    __hip_bfloat16* xw1b = (__hip_bfloat16*)aln(p, (size_t)NW * 128 * 2);
    __hip_bfloat16* xd1b = (__hip_bfloat16*)aln(p, (size_t)ND * 128 * 2);
    __hip_bfloat16* Wt   = (__hip_bfloat16*)aln(p, (size_t)1024 * 256 * 2);
    float* el0  = (float*)aln(p, (size_t)NW * 4 * 4);   // ww src logits
    float* er0  = (float*)aln(p, (size_t)NW * 4 * 4);   // ww dst logits
    float* el1  = (float*)aln(p, (size_t)NW * 4 * 4);   // wd src logits (word rows)
    float* er1  = (float*)aln(p, (size_t)ND * 4 * 4);   // wd dst logits (doc rows)
    float* Wr   = (float*)aln(p, 4096);
    // CSR ww
    int* rp_ww  = (int*)aln(p, (size_t)(NW + 1) * 4);
    int* deg_ww = (int*)aln(p, (size_t)NW * 2 * 4);   // deg + cnt, one memset
    int* ss_ww  = (int*)aln(p, (size_t)EWW * 4);
    // CSR wd
    int* rp_wd  = (int*)aln(p, (size_t)(ND + 1) * 4);
    int* deg_wd = (int*)aln(p, (size_t)ND * 2 * 4);
    int* ss_wd  = (int*)aln(p, (size_t)EWD * 4);
    int* bsum   = (int*)aln(p, 1024);

    float* out_xw = (float*)d_out;
    float* out_xd = out_xw + (size_t)NW * 128;

    // ---- cast input features ----
    cast_bf16_v4<<<(NW * 256 / 4 + 255) / 256, 256, 0, stream>>>(
        (const float4*)xw, (uint2*)xwb, NW * 256 / 4);

    // ---- CSR build (once per graph, reused by both layers) ----
    build_csr(ww_src, ww_dst, NW, EWW, rp_ww, deg_ww, bsum, ss_ww, stream);
    build_csr(wd_src, wd_dst, ND, EWD, rp_wd, deg_wd, bsum, ss_wd, stream);

    const int GEMM_BLOCKS = 8 * (NW / 128);   // 5000
    const int NBW = (NW + 3) / 4, NBD = (ND + 3) / 4;

    // ================= layer 0 (K=256) =================
    transpose_w2<<<(1024 * 256 + 255) / 256, 256, 0, stream>>>(W_ww0, W_wd0, Wt, 256);
    gemm_epi<<<GEMM_BLOCKS, 256, 0, stream>>>(xwb, Wt, z, al_ww0, ar_ww0, al_wd0,
                                              el0, er0, el1, NW, 256);
    make_wr<<<(256 * 4 + 255) / 256, 256, 0, stream>>>(W_wd0, ar_wd0, Wr, 256);
    attn_f32<<<(ND + 3) / 4, 256, 0, stream>>>(xd, Wr, er1, ND, 256);
    softmax_agg2<<<NBW + NBD, 256, 0, stream>>>(
        rp_ww, ss_ww, el0, er0, b_ww0,
        rp_wd, ss_wd, el1, er1, b_wd0,
        z, nullptr, xw1b, nullptr, xd1b, NBW);

    // ================= layer 1 (K=128) =================
    transpose_w2<<<(1024 * 128 + 255) / 256, 256, 0, stream>>>(W_ww1, W_wd1, Wt, 128);
    gemm_epi<<<GEMM_BLOCKS, 256, 0, stream>>>(xw1b, Wt, z, al_ww1, ar_ww1, al_wd1,
                                              el0, er0, el1, NW, 128);
    make_wr<<<(128 * 4 + 255) / 256, 256, 0, stream>>>(W_wd1, ar_wd1, Wr, 128);
    attn_bf16<<<(ND + 3) / 4, 256, 0, stream>>>(xd1b, Wr, er1, ND, 128);
    softmax_agg2<<<NBW + NBD, 256, 0, stream>>>(
        rp_ww, ss_ww, el0, er0, b_ww1,
        rp_wd, ss_wd, el1, er1, b_wd1,
        z, out_xw, nullptr, out_xd, nullptr, NBW);
}

// Round 5
// 519.781 us; speedup vs baseline: 1.2100x; 1.0953x over previous
//
#include <hip/hip_runtime.h>
#include <hip/hip_bf16.h>
#include <cstddef>
#include <cfloat>

#define NW 80000
#define ND 16000
#define EWW 200000
#define EWD 200000

typedef short v8s __attribute__((ext_vector_type(8)));
typedef float v4f __attribute__((ext_vector_type(4)));

static __device__ __forceinline__ float blo(unsigned u) { return __uint_as_float(u << 16); }
static __device__ __forceinline__ float bhi(unsigned u) { return __uint_as_float(u & 0xffff0000u); }

// async global->LDS 16B copy: lane i of the wave writes lds_base + i*16
static __device__ __forceinline__ void gl2lds16(const void* g, void* l) {
    __builtin_amdgcn_global_load_lds((__attribute__((address_space(1))) void*)g,
                                     (__attribute__((address_space(3))) void*)l, 16, 0, 0);
}

// ---------- fp32 -> bf16 cast, x4 vectorized ----------
__global__ void cast_bf16_v4(const float4* __restrict__ x, uint2* __restrict__ xb, int n4) {
    int i = blockIdx.x * blockDim.x + threadIdx.x;
    if (i >= n4) return;
    float4 v = x[i];
    __hip_bfloat162 a, b;
    a.x = __float2bfloat16(v.x); a.y = __float2bfloat16(v.y);
    b.x = __float2bfloat16(v.z); b.y = __float2bfloat16(v.w);
    uint2 o;
    o.x = *(unsigned*)&a; o.y = *(unsigned*)&b;
    xb[i] = o;
}

// ---------- fused weight prep for BOTH layers in one dispatch ----------
// blocks [0,1024): transpose L0 -> Wt0 (K=256); [1024,1536): transpose L1 -> Wt1 (K=128)
// [1536,1540): make_wr L0 -> Wr0; [1540,1542): make_wr L1 -> Wr1
__global__ __launch_bounds__(256) void prep_all(
        const float* __restrict__ W_ww0, const float* __restrict__ W_wd0,
        const float* __restrict__ W_ww1, const float* __restrict__ W_wd1,
        const float* __restrict__ ar_wd0, const float* __restrict__ ar_wd1,
        __hip_bfloat16* __restrict__ Wt0, __hip_bfloat16* __restrict__ Wt1,
        float* __restrict__ Wr0, float* __restrict__ Wr1) {
    int bid = blockIdx.x, tid = threadIdx.x;
    if (bid < 1024) {
        int i = bid * 256 + tid;                 // 1024*256 elems, K=256
        int n = i >> 8, k = i & 255;
        float v = (n < 512) ? W_ww0[k * 512 + n] : W_wd0[k * 512 + (n - 512)];
        Wt0[n * 256 + k] = __float2bfloat16(v);
    } else if (bid < 1536) {
        int i = (bid - 1024) * 256 + tid;        // 1024*128 elems, K=128
        int n = i >> 7, k = i & 127;
        float v = (n < 512) ? W_ww1[k * 512 + n] : W_wd1[k * 512 + (n - 512)];
        Wt1[n * 128 + k] = __float2bfloat16(v);
    } else if (bid < 1540) {
        int i = (bid - 1536) * 256 + tid;        // 256*4
        int k = i >> 2, h = i & 3;
        float sr = 0.f;
        const float* wr = W_wd0 + (size_t)k * 512 + h * 128;
        const float* arr = ar_wd0 + h * 128;
        for (int f = 0; f < 128; f++) sr += wr[f] * arr[f];
        Wr0[k * 4 + h] = sr;
    } else {
        int i = (bid - 1540) * 256 + tid;        // 128*4
        int k = i >> 2, h = i & 3;
        float sr = 0.f;
        const float* wr = W_wd1 + (size_t)k * 512 + h * 128;
        const float* arr = ar_wd1 + h * 128;
        for (int f = 0; f < 128; f++) sr += wr[f] * arr[f];
        Wr1[k * 4 + h] = sr;
    }
}

// ---------- er = x @ Wr ([N,4]); one wave per row; fp32 x ----------
__global__ __launch_bounds__(256) void attn_f32(const float* __restrict__ x,
                                                const float* __restrict__ Wv,
                                                float* __restrict__ out, int N, int K) {
    int wave = threadIdx.x >> 6, lane = threadIdx.x & 63;
    int row = blockIdx.x * 4 + wave;
    if (row >= N) return;
    const float* xr = x + (size_t)row * K;
    float a0 = 0.f, a1 = 0.f, a2 = 0.f, a3 = 0.f;
    for (int k = lane; k < K; k += 64) {
        float v = xr[k];
        const float* w = Wv + k * 4;
        a0 += v * w[0]; a1 += v * w[1]; a2 += v * w[2]; a3 += v * w[3];
    }
#pragma unroll
    for (int off = 32; off; off >>= 1) {
        a0 += __shfl_down(a0, off); a1 += __shfl_down(a1, off);
        a2 += __shfl_down(a2, off); a3 += __shfl_down(a3, off);
    }
    if (lane == 0) {
        out[row * 4 + 0] = a0; out[row * 4 + 1] = a1;
        out[row * 4 + 2] = a2; out[row * 4 + 3] = a3;
    }
}

// ---------- bf16-x variant ----------
__global__ __launch_bounds__(256) void attn_bf16(const __hip_bfloat16* __restrict__ x,
                                                 const float* __restrict__ Wv,
                                                 float* __restrict__ out, int N, int K) {
    int wave = threadIdx.x >> 6, lane = threadIdx.x & 63;
    int row = blockIdx.x * 4 + wave;
    if (row >= N) return;
    const __hip_bfloat16* xr = x + (size_t)row * K;
    float a0 = 0.f, a1 = 0.f, a2 = 0.f, a3 = 0.f;
    for (int k = lane; k < K; k += 64) {
        float v = __bfloat162float(xr[k]);
        const float* w = Wv + k * 4;
        a0 += v * w[0]; a1 += v * w[1]; a2 += v * w[2]; a3 += v * w[3];
    }
#pragma unroll
    for (int off = 32; off; off >>= 1) {
        a0 += __shfl_down(a0, off); a1 += __shfl_down(a1, off);
        a2 += __shfl_down(a2, off); a3 += __shfl_down(a3, off);
    }
    if (lane == 0) {
        out[row * 4 + 0] = a0; out[row * 4 + 1] = a1;
        out[row * 4 + 2] = a2; out[row * 4 + 3] = a3;
    }
}

// ---------- merged bf16 MFMA GEMM (both relations) + attention-logit epilogue ----------
// z[M,1024] = A[M,K] @ [W_ww | W_wd]  (Bt = concat^T [1024,K]).  BM=128, BK=64.
// 512 threads / 8 waves per block (r4: 4 waves = 2 waves/SIMD gave 20% occupancy,
// MfmaUtil 17%, dur pinned at 98us — issue-starved, not BW-bound). Each wave owns
// 16 rows: half the per-wave MFMA/VALU, same LDS (64KB, 2 blocks/CU) -> 4 waves/SIMD.
// T3+T4 pipeline: raw s_barrier + counted vmcnt(4) (4 loads/wave/stage) so next
// tile's loads stay in flight across the barrier. T5 setprio around MFMA cluster.
__global__ __launch_bounds__(512) void gemm_epi(const __hip_bfloat16* __restrict__ A,
                                                const __hip_bfloat16* __restrict__ Bt,
                                                __hip_bfloat16* __restrict__ C,
                                                const float* __restrict__ al0,
                                                const float* __restrict__ ar0,
                                                const float* __restrict__ al1,
                                                float* __restrict__ el0,
                                                float* __restrict__ er0,
                                                float* __restrict__ el1,
                                                int M, int K) {
    const int N = 1024;
    __shared__ short AsF[2][128 * 64];   // 2 x 16 KB, row stride 64 shorts
    __shared__ short BsF[2][128 * 64];
    int tid = threadIdx.x;
    int wave = tid >> 6, lane = tid & 63;    // wave 0..7, 16 rows each
    int l16 = lane & 15, quad = lane >> 4;

    // ---- XCD swizzle ----
    int MT = M >> 7;              // number of 128-row m-tiles
    int full = MT >> 3;           // full 8-m-tile super-groups
    int bid = blockIdx.x;
    int h, mt;
    if (bid < (full << 6)) {
        int s = bid >> 6, r = bid & 63;
        h = r >> 3;
        mt = (s << 3) | (r & 7);
    } else {
        int r2 = bid - (full << 6);
        int rem = MT - (full << 3);
        h = r2 / rem;
        mt = (full << 3) + (r2 - h * rem);
    }
    bool isww = h < 4;
    int hh = isww ? h : h - 4;
    int bm = mt * 128, bn = h * 128;
    v4f acc[8] = {};

    int laneR = lane >> 3;                 // 0..7
    int laneC = (lane & 7) ^ laneR;        // swizzled 16B-chunk index
    const __hip_bfloat16* ga = A  + (size_t)(bm + wave * 16 + laneR) * K + laneC * 8;
    const __hip_bfloat16* gb = Bt + (size_t)(bn + wave * 16 + laneR) * K + laneC * 8;
    int lofs = (wave * 16) * 64;           // short offset of this wave's 16-row slab

    auto STAGE = [&](int buf, int k0) {
#pragma unroll
        for (int j = 0; j < 2; j++) {
            gl2lds16(ga + (size_t)(j * 8) * K + k0, &AsF[buf][lofs + j * 512]);
            gl2lds16(gb + (size_t)(j * 8) * K + k0, &BsF[buf][lofs + j * 512]);
        }
    };
    auto COMPUTE = [&](int buf) {
#pragma unroll
        for (int kh = 0; kh < 2; kh++) {
            int s = (kh * 4 + quad) ^ (l16 & 7);
            v8s a0, b[8];
            a0 = *(const v8s*)&AsF[buf][(wave * 16 + l16) * 64 + s * 8];
#pragma unroll
            for (int c = 0; c < 8; c++)
                b[c] = *(const v8s*)&BsF[buf][(c * 16 + l16) * 64 + s * 8];
            __builtin_amdgcn_s_setprio(1);
#pragma unroll
            for (int c = 0; c < 8; c++)
                acc[c] = __builtin_amdgcn_mfma_f32_16x16x32_bf16(a0, b[c], acc[c], 0, 0, 0);
            __builtin_amdgcn_s_setprio(0);
        }
    };

    // prologue: fill buf 0 with k=0 (4 loads/wave in flight)
    STAGE(0, 0);
    // main loop: 2 tiles per iteration, compile-time buffer indices.
    // K is a multiple of 128 here (256 or 128) -> tile count even.
    for (int k0 = 0; k0 < K; k0 += 128) {
        if (k0 + 64 < K) {
            STAGE(1, k0 + 64);                                   // +4 in flight
            asm volatile("s_waitcnt vmcnt(4)" ::: "memory");     // tile(k0) landed
        } else {
            asm volatile("s_waitcnt vmcnt(0)" ::: "memory");
        }
        __builtin_amdgcn_s_barrier();                            // all waves: buf0 valid
        asm volatile("" ::: "memory");
        COMPUTE(0);
        __builtin_amdgcn_s_barrier();                            // all waves done reading buf0
        asm volatile("" ::: "memory");
        if (k0 + 128 < K) {
            STAGE(0, k0 + 128);
            asm volatile("s_waitcnt vmcnt(4)" ::: "memory");     // tile(k0+64) landed
        } else {
            asm volatile("s_waitcnt vmcnt(0)" ::: "memory");
        }
        __builtin_amdgcn_s_barrier();                            // buf1 valid
        asm volatile("" ::: "memory");
        COMPUTE(1);
        __builtin_amdgcn_s_barrier();                            // done reading buf1
        asm volatile("" ::: "memory");
    }

    // ---- C writeback via LDS re-stage (wave-private 16-row slabs; no barrier needed:
    // the final loop barrier ordered all COMPUTE reads before these writes) ----
    short* cs = &AsF[0][0];                  // flat 32KB = [128][128] bf16, rotated chunks
#pragma unroll
    for (int c = 0; c < 8; c++)
#pragma unroll
        for (int i = 0; i < 4; i++) {
            int lr = wave * 16 + quad * 4 + i;
            int sIdx = c * 16 + l16;
            int chunk = ((sIdx >> 3) + 2 * (lr >> 2)) & 15;   // rotate per 4-row group
            cs[lr * 128 + (chunk << 3) + (sIdx & 7)] =
                (short)__bfloat16_as_ushort(__float2bfloat16(acc[c][i]));
        }
    {
        short* Cs = (short*)C;
#pragma unroll
        for (int j = 0; j < 4; j++) {
            int lr = wave * 16 + j * 4 + (lane >> 4);     // local row
            int cc = lane & 15;                           // logical 16B chunk
            int chunk = (cc + 2 * (lr >> 2)) & 15;        // physical chunk
            v8s val = *(const v8s*)&cs[lr * 128 + (chunk << 3)];
            *(v8s*)&Cs[(size_t)(bm + lr) * N + bn + cc * 8] = val;
        }
    }
    // epilogue: el (and er for ww heads) via per-lane dot + 16-lane shuffle reduce
    const float* alp = isww ? al0 : al1;
    float* elp = isww ? el0 : el1;
    float* erp = isww ? er0 : nullptr;
    float alv[8], arv[8];
#pragma unroll
    for (int c = 0; c < 8; c++) {
        alv[c] = alp[hh * 128 + c * 16 + l16];
        arv[c] = isww ? ar0[hh * 128 + c * 16 + l16] : 0.f;
    }
#pragma unroll
    for (int i = 0; i < 4; i++) {
        float pl = 0.f, pr = 0.f;
#pragma unroll
        for (int c = 0; c < 8; c++) {
            pl += acc[c][i] * alv[c];
            pr += acc[c][i] * arv[c];
        }
#pragma unroll
        for (int off = 1; off < 16; off <<= 1) {
            pl += __shfl_xor(pl, off);
            pr += __shfl_xor(pr, off);
        }
        if (l16 == 0) {
            int row = bm + wave * 16 + quad * 4 + i;
            elp[(size_t)row * 4 + hh] = pl;
            if (erp) erp[(size_t)row * 4 + hh] = pr;
        }
    }
}

// ---------- fused CSR build, BOTH relations per dispatch ----------
__global__ void hist2(const int* __restrict__ dst_w, const int* __restrict__ dst_d,
                      int* __restrict__ deg_w, int* __restrict__ deg_d) {
    int t = blockIdx.x * blockDim.x + threadIdx.x;
    if (t < EWW) atomicAdd(&deg_w[dst_w[t]], 1);
    if (t < EWD) atomicAdd(&deg_d[dst_d[t]], 1);
}

__global__ __launch_bounds__(256) void scan_block2(
        const int* __restrict__ deg_w, int* __restrict__ rp_w, int* __restrict__ bsum_w,
        const int* __restrict__ deg_d, int* __restrict__ rp_d, int* __restrict__ bsum_d,
        int nbw) {
    const int* deg; int *rp, *bsum; int N, b;
    if ((int)blockIdx.x < nbw) { deg = deg_w; rp = rp_w; bsum = bsum_w; N = NW; b = blockIdx.x; }
    else { deg = deg_d; rp = rp_d; bsum = bsum_d; N = ND; b = blockIdx.x - nbw; }
    __shared__ int ts[256];
    int tid = threadIdx.x;
    int base = b * 1024 + tid * 4;
    int v0 = 0, v1 = 0, v2 = 0, v3 = 0;
    if (base + 3 < N) {
        int4 q = *(const int4*)(deg + base);
        v0 = q.x; v1 = q.y; v2 = q.z; v3 = q.w;
    } else {
        if (base + 0 < N) v0 = deg[base + 0];
        if (base + 1 < N) v1 = deg[base + 1];
        if (base + 2 < N) v2 = deg[base + 2];
        if (base + 3 < N) v3 = deg[base + 3];
    }
    int s = v0 + v1 + v2 + v3;
    ts[tid] = s;
    __syncthreads();
    for (int off = 1; off < 256; off <<= 1) {
        int t = (tid >= off) ? ts[tid - off] : 0;
        __syncthreads();
        ts[tid] += t;
        __syncthreads();
    }
    int excl = ts[tid] - s;
    if (tid == 255) bsum[b] = ts[255];
    if (base + 0 < N) rp[base + 0] = excl;
    if (base + 1 < N) rp[base + 1] = excl + v0;
    if (base + 2 < N) rp[base + 2] = excl + v0 + v1;
    if (base + 3 < N) rp[base + 3] = excl + v0 + v1 + v2;
}

__global__ __launch_bounds__(256) void scan_bsum2(int* __restrict__ bsum_w, int nbw,
                                                  int* __restrict__ bsum_d, int nbd) {
    int* bsum = blockIdx.x == 0 ? bsum_w : bsum_d;
    int nb = blockIdx.x == 0 ? nbw : nbd;
    __shared__ int ts[256];
    int tid = threadIdx.x;
    int v = (tid < nb) ? bsum[tid] : 0;
    ts[tid] = v;
    __syncthreads();
    for (int off = 1; off < 256; off <<= 1) {
        int t = (tid >= off) ? ts[tid - off] : 0;
        __syncthreads();
        ts[tid] += t;
        __syncthreads();
    }
    if (tid < nb) bsum[tid] = ts[tid] - v;
}

__global__ __launch_bounds__(256) void add_off2(
        int* __restrict__ rp_w, const int* __restrict__ bsum_w,
        int* __restrict__ rp_d, const int* __restrict__ bsum_d, int nbw) {
    int *rp; const int* bsum; int N, E, b;
    if ((int)blockIdx.x < nbw) { rp = rp_w; bsum = bsum_w; N = NW; E = EWW; b = blockIdx.x; }
    else { rp = rp_d; bsum = bsum_d; N = ND; E = EWD; b = blockIdx.x - nbw; }
    int tid = threadIdx.x;
    int base = b * 1024 + tid * 4;
    int o = bsum[b];
    if (base + 3 < N) {
        int4 q = *(const int4*)(rp + base);
        q.x += o; q.y += o; q.z += o; q.w += o;
        *(int4*)(rp + base) = q;
    } else {
        if (base + 0 < N) rp[base + 0] += o;
        if (base + 1 < N) rp[base + 1] += o;
        if (base + 2 < N) rp[base + 2] += o;
        if (base + 3 < N) rp[base + 3] += o;
    }
    if (b == 0 && tid == 0) rp[N] = E;
}

__global__ void scatter2(const int* __restrict__ src_w, const int* __restrict__ dst_w,
                         const int* __restrict__ rp_w, int* __restrict__ cnt_w,
                         int* __restrict__ ss_w,
                         const int* __restrict__ src_d, const int* __restrict__ dst_d,
                         const int* __restrict__ rp_d, int* __restrict__ cnt_d,
                         int* __restrict__ ss_d) {
    int t = blockIdx.x * blockDim.x + threadIdx.x;
    if (t < EWW) {
        int d = dst_w[t];
        int pos = rp_w[d] + atomicAdd(&cnt_w[d], 1);
        ss_w[pos] = src_w[t];
    }
    if (t < EWD) {
        int d = dst_d[t];
        int pos = rp_d[d] + atomicAdd(&cnt_d[d], 1);
        ss_d[pos] = src_d[t];
    }
}

// ---------- fused edge-softmax + aggregate, BOTH relations in one dispatch ----------
// One wave per dst. Per-lane OWN-HEAD layout: lane covers 8 consecutive bf16 cols
// of head (lane>>4) via ONE dwordx4 per edge. Online softmax per-lane for its own
// head; cross-head sum + bias at the end via 2 shfl_xor. Chunk-4 edge batching
// with src-index prefetch.
__global__ __launch_bounds__(256) void softmax_agg2(
        const int* __restrict__ rp_w, const int* __restrict__ ss_w,
        const float* __restrict__ el_w, const float* __restrict__ er_w,
        const float* __restrict__ b_w,
        const int* __restrict__ rp_d, const int* __restrict__ ss_d,
        const float* __restrict__ el_d, const float* __restrict__ er_d,
        const float* __restrict__ b_d,
        const __hip_bfloat16* __restrict__ z,
        float* __restrict__ outf_w, __hip_bfloat16* __restrict__ outb_w,
        float* __restrict__ outf_d, __hip_bfloat16* __restrict__ outb_d,
        int nbw) {
    int wave = threadIdx.x >> 6, lane = threadIdx.x & 63;
    int h0 = lane >> 4, l16 = lane & 15;
    const int *rp, *ss;
    const float *el, *er, *bv;
    float* outf;
    __hip_bfloat16* outb;
    int d, Nd, zoff;
    if ((int)blockIdx.x < nbw) {
        rp = rp_w; ss = ss_w; el = el_w; er = er_w; bv = b_w;
        outf = outf_w; outb = outb_w; zoff = 0; Nd = NW;
        d = blockIdx.x * 4 + wave;
    } else {
        rp = rp_d; ss = ss_d; el = el_d; er = er_d; bv = b_d;
        outf = outf_d; outb = outb_d; zoff = 512; Nd = ND;
        d = (blockIdx.x - nbw) * 4 + wave;
    }
    if (d >= Nd) return;
    int i0 = rp[d], i1 = rp[d + 1];
    float er_own = er[(size_t)d * 4 + h0];
    float bb[8];
#pragma unroll
    for (int t = 0; t < 8; t++) bb[t] = bv[h0 * 128 + l16 * 8 + t];

    float m = -FLT_MAX, l = 0.f;
    float acc[8];
#pragma unroll
    for (int t = 0; t < 8; t++) acc[t] = 0.f;

    const __hip_bfloat16* zb = z + zoff;
    auto PROC = [&](float elv, const uint4& zv) {
        float e = elv + er_own;
        e = e > 0.f ? e : 0.2f * e;                 // leaky_relu(0.2)
        float nm = fmaxf(m, e);
        float sc = __expf(m - nm);
        float p  = __expf(e - nm);
        m = nm;
        l = l * sc + p;
        acc[0] = acc[0] * sc + p * blo(zv.x);
        acc[1] = acc[1] * sc + p * bhi(zv.x);
        acc[2] = acc[2] * sc + p * blo(zv.y);
        acc[3] = acc[3] * sc + p * bhi(zv.y);
        acc[4] = acc[4] * sc + p * blo(zv.z);
        acc[5] = acc[5] * sc + p * bhi(zv.z);
        acc[6] = acc[6] * sc + p * blo(zv.w);
        acc[7] = acc[7] * sc + p * bhi(zv.w);
    };

    if (i0 < i1) {
        int last = i1 - 1;
        int s0 = ss[i0];
        int s1 = ss[min(i0 + 1, last)];
        int s2 = ss[min(i0 + 2, last)];
        int s3 = ss[min(i0 + 3, last)];
        for (int i = i0; i < i1; i += 4) {
            float e0 = el[(size_t)s0 * 4 + h0];
            float e1 = el[(size_t)s1 * 4 + h0];
            float e2 = el[(size_t)s2 * 4 + h0];
            float e3 = el[(size_t)s3 * 4 + h0];
            uint4 z0 = ((const uint4*)(zb + (size_t)s0 * 1024))[lane];
            uint4 z1 = ((const uint4*)(zb + (size_t)s1 * 1024))[lane];
            uint4 z2 = ((const uint4*)(zb + (size_t)s2 * 1024))[lane];
            uint4 z3 = ((const uint4*)(zb + (size_t)s3 * 1024))[lane];
            s0 = ss[min(i + 4, last)];
            s1 = ss[min(i + 5, last)];
            s2 = ss[min(i + 6, last)];
            s3 = ss[min(i + 7, last)];
            int rem = i1 - i;
            PROC(e0, z0);
            if (rem > 1) PROC(e1, z1);
            if (rem > 2) PROC(e2, z2);
            if (rem > 3) PROC(e3, z3);
        }
    }

    float inv = l > 0.f ? 1.f / l : 0.f;
    float v[8];
#pragma unroll
    for (int t = 0; t < 8; t++) v[t] = acc[t] * inv + bb[t];
#pragma unroll
    for (int t = 0; t < 8; t++) {
        v[t] += __shfl_xor(v[t], 16);
        v[t] += __shfl_xor(v[t], 32);
    }
#pragma unroll
    for (int t = 0; t < 8; t++) v[t] = fmaxf(v[t], 0.f);   // relu
    if (lane < 16) {
        if (outf) {
            float4 o0 = make_float4(v[0], v[1], v[2], v[3]);
            float4 o1 = make_float4(v[4], v[5], v[6], v[7]);
            *(float4*)(outf + (size_t)d * 128 + l16 * 8)     = o0;
            *(float4*)(outf + (size_t)d * 128 + l16 * 8 + 4) = o1;
        } else {
            __hip_bfloat162 p01, p23, p45, p67;
            p01.x = __float2bfloat16(v[0]); p01.y = __float2bfloat16(v[1]);
            p23.x = __float2bfloat16(v[2]); p23.y = __float2bfloat16(v[3]);
            p45.x = __float2bfloat16(v[4]); p45.y = __float2bfloat16(v[5]);
            p67.x = __float2bfloat16(v[6]); p67.y = __float2bfloat16(v[7]);
            uint4 o;
            o.x = *(unsigned*)&p01; o.y = *(unsigned*)&p23;
            o.z = *(unsigned*)&p45; o.w = *(unsigned*)&p67;
            *(uint4*)(outb + (size_t)d * 128 + l16 * 8) = o;
        }
    }
}

static inline char* aln(char*& p, size_t bytes) {
    char* r = p;
    p += (bytes + 255) & ~(size_t)255;
    return r;
}

extern "C" void kernel_launch(void* const* d_in, const int* in_sizes, int n_in,
                              void* d_out, int out_size, void* d_ws, size_t ws_size,
                              hipStream_t stream) {
    const float* xw     = (const float*)d_in[0];
    const float* xd     = (const float*)d_in[1];
    const float* W_ww0  = (const float*)d_in[2];
    const float* al_ww0 = (const float*)d_in[3];
    const float* ar_ww0 = (const float*)d_in[4];
    const float* b_ww0  = (const float*)d_in[5];
    const float* W_wd0  = (const float*)d_in[6];
    const float* al_wd0 = (const float*)d_in[7];
    const float* ar_wd0 = (const float*)d_in[8];
    const float* b_wd0  = (const float*)d_in[9];
    const float* W_ww1  = (const float*)d_in[10];
    const float* al_ww1 = (const float*)d_in[11];
    const float* ar_ww1 = (const float*)d_in[12];
    const float* b_ww1  = (const float*)d_in[13];
    const float* W_wd1  = (const float*)d_in[14];
    const float* al_wd1 = (const float*)d_in[15];
    const float* ar_wd1 = (const float*)d_in[16];
    const float* b_wd1  = (const float*)d_in[17];
    const int* ww_src   = (const int*)d_in[18];
    const int* ww_dst   = (const int*)d_in[19];
    const int* wd_src   = (const int*)d_in[20];
    const int* wd_dst   = (const int*)d_in[21];

    // ---- workspace carve ----
    char* p = (char*)d_ws;
    __hip_bfloat16* z    = (__hip_bfloat16*)aln(p, (size_t)NW * 1024 * 2);  // 164 MB
    __hip_bfloat16* xwb  = (__hip_bfloat16*)aln(p, (size_t)NW * 256 * 2);
    __hip_bfloat16* xw1b = (__hip_bfloat16*)aln(p, (size_t)NW * 128 * 2);
    __hip_bfloat16* xd1b = (__hip_bfloat16*)aln(p, (size_t)ND * 128 * 2);
    __hip_bfloat16* Wt0  = (__hip_bfloat16*)aln(p, (size_t)1024 * 256 * 2);
    __hip_bfloat16* Wt1  = (__hip_bfloat16*)aln(p, (size_t)1024 * 128 * 2);
    float* el0  = (float*)aln(p, (size_t)NW * 4 * 4);   // ww src logits
    float* er0  = (float*)aln(p, (size_t)NW * 4 * 4);   // ww dst logits
    float* el1  = (float*)aln(p, (size_t)NW * 4 * 4);   // wd src logits (word rows)
    float* er1  = (float*)aln(p, (size_t)ND * 4 * 4);   // wd dst logits (doc rows)
    float* Wr0  = (float*)aln(p, 4096);
    float* Wr1  = (float*)aln(p, 4096);
    // CSR — deg arrays contiguous so one memset covers both
    int* deg_ww = (int*)aln(p, (size_t)NW * 2 * 4);   // deg + cnt
    int* deg_wd = (int*)aln(p, (size_t)ND * 2 * 4);
    int* rp_ww  = (int*)aln(p, (size_t)(NW + 1) * 4);
    int* ss_ww  = (int*)aln(p, (size_t)EWW * 4);
    int* rp_wd  = (int*)aln(p, (size_t)(ND + 1) * 4);
    int* ss_wd  = (int*)aln(p, (size_t)EWD * 4);
    int* bsum   = (int*)aln(p, 2048);
    int* bsum_w = bsum;           // 79 used
    int* bsum_d = bsum + 256;     // 16 used

    float* out_xw = (float*)d_out;
    float* out_xd = out_xw + (size_t)NW * 128;

    const int NBW_S = (NW + 1023) / 1024;   // 79 scan blocks (ww)
    const int NBD_S = (ND + 1023) / 1024;   // 16 scan blocks (wd)

    // ---- cast input features ----
    cast_bf16_v4<<<(NW * 256 / 4 + 255) / 256, 256, 0, stream>>>(
        (const float4*)xw, (uint2*)xwb, NW * 256 / 4);

    // ---- fused CSR build (both relations) ----
    hipMemsetAsync(deg_ww, 0, (size_t)(NW * 2 + ND * 2) * 4, stream);
    hist2<<<(EWW + 255) / 256, 256, 0, stream>>>(ww_dst, wd_dst, deg_ww, deg_wd);
    scan_block2<<<NBW_S + NBD_S, 256, 0, stream>>>(deg_ww, rp_ww, bsum_w,
                                                   deg_wd, rp_wd, bsum_d, NBW_S);
    scan_bsum2<<<2, 256, 0, stream>>>(bsum_w, NBW_S, bsum_d, NBD_S);
    add_off2<<<NBW_S + NBD_S, 256, 0, stream>>>(rp_ww, bsum_w, rp_wd, bsum_d, NBW_S);
    scatter2<<<(EWW + 255) / 256, 256, 0, stream>>>(ww_src, ww_dst, rp_ww, deg_ww + NW, ss_ww,
                                                    wd_src, wd_dst, rp_wd, deg_wd + ND, ss_wd);

    // ---- weight prep for both layers, one dispatch ----
    prep_all<<<1542, 256, 0, stream>>>(W_ww0, W_wd0, W_ww1, W_wd1, ar_wd0, ar_wd1,
                                       Wt0, Wt1, Wr0, Wr1);
    attn_f32<<<(ND + 3) / 4, 256, 0, stream>>>(xd, Wr0, er1, ND, 256);

    const int GEMM_BLOCKS = 8 * (NW / 128);   // 5000
    const int NBW = (NW + 3) / 4, NBD = (ND + 3) / 4;

    // ================= layer 0 (K=256) =================
    gemm_epi<<<GEMM_BLOCKS, 512, 0, stream>>>(xwb, Wt0, z, al_ww0, ar_ww0, al_wd0,
                                              el0, er0, el1, NW, 256);
    softmax_agg2<<<NBW + NBD, 256, 0, stream>>>(
        rp_ww, ss_ww, el0, er0, b_ww0,
        rp_wd, ss_wd, el1, er1, b_wd0,
        z, nullptr, xw1b, nullptr, xd1b, NBW);

    // ================= layer 1 (K=128) =================
    gemm_epi<<<GEMM_BLOCKS, 512, 0, stream>>>(xw1b, Wt1, z, al_ww1, ar_ww1, al_wd1,
                                              el0, er0, el1, NW, 128);
    attn_bf16<<<(ND + 3) / 4, 256, 0, stream>>>(xd1b, Wr1, er1, ND, 128);
    softmax_agg2<<<NBW + NBD, 256, 0, stream>>>(
        rp_ww, ss_ww, el0, er0, b_ww1,
        rp_wd, ss_wd, el1, er1, b_wd1,
        z, out_xw, nullptr, out_xd, nullptr, NBW);
}